// Round 1
// baseline (8237.579 us; speedup 1.0000x reference)
//
#include <hip/hip_runtime.h>
#include <math.h>

#define D_MODEL 512
#define N_HEADS 8
#define D_KH    64
#define D_FF    2048
#define N_LAYERS 4
#define BSZ     4
#define SEQ     1024

// ---------------- embedding + sinusoid positional encoding ----------------
__global__ void embed_kernel(const int* __restrict__ dec, const float* __restrict__ emb,
                             float* __restrict__ x) {
    int idx = blockIdx.x * blockDim.x + threadIdx.x;  // over BSZ*SEQ*D_MODEL
    int d  = idx % D_MODEL;
    int bs = idx / D_MODEL;
    int s  = bs % SEQ;
    int tok = dec[bs];
    float pos = (float)(s + 5);                        // reference indexes positions 5..S+4
    float e = (float)(d & ~1) / (float)D_MODEL;
    float denom = powf(10000.0f, e);
    float ang = pos / denom;
    float pe = (d & 1) ? cosf(ang) : sinf(ang);
    x[idx] = emb[(size_t)tok * D_MODEL + d] + pe;
}

// ---------------- tiled fp32 GEMM: C[M,N] = A[M,K] @ W[K,N] + bias, optional ReLU -----
template<int RELU>
__global__ void gemm_bias_kernel(const float* __restrict__ A, const float* __restrict__ W,
                                 const float* __restrict__ bias, float* __restrict__ C,
                                 int M, int N, int K) {
    const int BM = 64, BN = 64, BK = 16;
    __shared__ float As[BK][BM + 1];
    __shared__ float Bs[BK][BN + 1];
    int m0 = blockIdx.y * BM;
    int n0 = blockIdx.x * BN;
    int t  = threadIdx.x;           // 256 threads
    int tx = t % 16, ty = t / 16;
    float acc[4][4] = {};
    for (int k0 = 0; k0 < K; k0 += BK) {
        #pragma unroll
        for (int i = 0; i < 4; i++) {            // A tile 64x16
            int lin = t + i * 256;
            int m = lin / BK, k = lin % BK;
            As[k][m] = A[(size_t)(m0 + m) * K + k0 + k];
        }
        #pragma unroll
        for (int i = 0; i < 4; i++) {            // W tile 16x64
            int lin = t + i * 256;
            int k = lin / BN, n = lin % BN;
            Bs[k][n] = W[(size_t)(k0 + k) * N + n0 + n];
        }
        __syncthreads();
        #pragma unroll
        for (int k = 0; k < BK; k++) {
            float a[4], b[4];
            #pragma unroll
            for (int i = 0; i < 4; i++) a[i] = As[k][ty * 4 + i];
            #pragma unroll
            for (int j = 0; j < 4; j++) b[j] = Bs[k][tx * 4 + j];
            #pragma unroll
            for (int i = 0; i < 4; i++)
                #pragma unroll
                for (int j = 0; j < 4; j++)
                    acc[i][j] += a[i] * b[j];
        }
        __syncthreads();
    }
    #pragma unroll
    for (int i = 0; i < 4; i++) {
        int m = m0 + ty * 4 + i;
        #pragma unroll
        for (int j = 0; j < 4; j++) {
            int n = n0 + tx * 4 + j;
            float v = acc[i][j] + bias[n];
            if (RELU) v = fmaxf(v, 0.0f);
            C[(size_t)m * N + n] = v;
        }
    }
}

// ---------------- fused attention: online softmax, never materializes SxS ------------
// Layout of Q/K/V/O: [B, S, H*D_KH] with head h at cols h*64..h*64+63.
// attend where (ids[b,k]==0) || (causal && k<=q); masked scores = -1e9 (after 1/8 scale).
__global__ void attn_kernel(const float* __restrict__ Q, const float* __restrict__ K,
                            const float* __restrict__ V, const int* __restrict__ ids,
                            float* __restrict__ O, int Sq, int Sk, int causal) {
    __shared__ float Ks[64][65];
    __shared__ float Vs[64][65];
    __shared__ float qs[4][64];
    __shared__ float ps[4][64];
    int blk = blockIdx.x;
    int qt = blk % (Sq / 4);
    int bh = blk / (Sq / 4);
    int h = bh % N_HEADS;
    int b = bh / N_HEADS;
    int t = threadIdx.x;
    int w = t / 64, lane = t % 64;
    int q = qt * 4 + w;
    qs[w][lane] = Q[((size_t)(b * Sq + q)) * D_MODEL + h * D_KH + lane];

    float m = -INFINITY, l = 0.0f, ctx = 0.0f;
    for (int k0 = 0; k0 < Sk; k0 += 64) {
        __syncthreads();
        #pragma unroll
        for (int i = 0; i < 16; i++) {
            int lin = t + i * 256;
            int r = lin / 64, d = lin % 64;
            size_t g = ((size_t)(b * Sk + k0 + r)) * D_MODEL + h * D_KH + d;
            Ks[r][d] = K[g];
            Vs[r][d] = V[g];
        }
        __syncthreads();
        float s = 0.0f;
        #pragma unroll
        for (int d = 0; d < 64; d++) s += qs[w][d] * Ks[lane][d];
        int k = k0 + lane;
        bool att = (ids[b * Sk + k] == 0) || (causal && k <= q);
        s = att ? s * 0.125f : -1e9f;
        float mt = s;
        #pragma unroll
        for (int o = 32; o > 0; o >>= 1) mt = fmaxf(mt, __shfl_xor(mt, o));
        float mn = fmaxf(m, mt);
        float p = expf(s - mn);
        float sc = expf(m - mn);            // m=-inf first iter -> 0
        float wsum = p;
        #pragma unroll
        for (int o = 32; o > 0; o >>= 1) wsum += __shfl_xor(wsum, o);
        l = l * sc + wsum;
        ctx *= sc;
        ps[w][lane] = p;
        #pragma unroll
        for (int kk = 0; kk < 64; kk++) ctx += ps[w][kk] * Vs[kk][lane];
        m = mn;
    }
    O[((size_t)(b * Sq + q)) * D_MODEL + h * D_KH + lane] = ctx / l;
}

// ---------------- layernorm(f + h) with gain/bias, one wave per 512-row -------------
__global__ void ln_residual_kernel(const float* __restrict__ f, const float* __restrict__ h,
                                   const float* __restrict__ g, const float* __restrict__ bb,
                                   float* __restrict__ out) {
    int row  = blockIdx.x * 4 + threadIdx.x / 64;
    int lane = threadIdx.x % 64;
    const float* fr = f + (size_t)row * D_MODEL;
    const float* hr = h + (size_t)row * D_MODEL;
    float v[8];
    float s = 0.f;
    #pragma unroll
    for (int i = 0; i < 8; i++) {
        v[i] = fr[lane + i * 64] + hr[lane + i * 64];
        s += v[i];
    }
    #pragma unroll
    for (int o = 32; o > 0; o >>= 1) s += __shfl_xor(s, o);
    float mu = s * (1.0f / 512.0f);
    float ss = 0.f;
    #pragma unroll
    for (int i = 0; i < 8; i++) { float d = v[i] - mu; ss += d * d; }
    #pragma unroll
    for (int o = 32; o > 0; o >>= 1) ss += __shfl_xor(ss, o);
    float var = ss * (1.0f / 512.0f);
    float inv = 1.0f / sqrtf(var + 1e-6f);
    #pragma unroll
    for (int i = 0; i < 8; i++) {
        int d = lane + i * 64;
        out[(size_t)row * D_MODEL + d] = g[d] * (v[i] - mu) * inv + bb[d];
    }
}

extern "C" void kernel_launch(void* const* d_in, const int* in_sizes, int n_in,
                              void* d_out, int out_size, void* d_ws, size_t ws_size,
                              hipStream_t stream) {
    const int*   dec     = (const int*)d_in[0];
    const int*   enc_ids = (const int*)d_in[1];
    const float* enc_out = (const float*)d_in[2];
    const float* emb     = (const float*)d_in[3];
    const float* self_W  = (const float*)d_in[4];
    const float* self_b  = (const float*)d_in[5];
    const float* enc_W   = (const float*)d_in[6];
    const float* enc_b   = (const float*)d_in[7];
    const float* W1      = (const float*)d_in[8];
    const float* b1      = (const float*)d_in[9];
    const float* W2      = (const float*)d_in[10];
    const float* b2      = (const float*)d_in[11];
    const float* ln_g    = (const float*)d_in[12];
    const float* ln_b    = (const float*)d_in[13];
    float* out = (float*)d_out;

    const size_t NTOK = (size_t)BSZ * SEQ;      // 4096
    // workspace: x(8MB) + bA(8MB) + region(32MB shared by {bB,bC,bD} / bH) = 48MB
    float* x   = (float*)d_ws;
    float* bA  = x + NTOK * D_MODEL;
    float* reg = bA + NTOK * D_MODEL;
    float* bB  = reg;
    float* bC  = reg + NTOK * D_MODEL;
    float* bD  = reg + 2 * NTOK * D_MODEL;
    float* bH  = reg;                            // NTOK * D_FF, reused after attention

    dim3 blk(256);
    embed_kernel<<<dim3((unsigned)(NTOK * D_MODEL / 256)), blk, 0, stream>>>(dec, emb, x);

    int M = (int)NTOK;
    dim3 gp (D_MODEL / 64, M / 64);
    dim3 gf1(D_FF   / 64, M / 64);
    dim3 gf2(D_MODEL / 64, M / 64);
    int nAttnBlk = BSZ * N_HEADS * (SEQ / 4);

    const size_t WSTRIDE = (size_t)D_MODEL * D_MODEL;
    for (int L = 0; L < N_LAYERS; L++) {
        const float* sW = self_W + (size_t)L * 4 * WSTRIDE;
        const float* sb = self_b + (size_t)L * 4 * D_MODEL;
        const float* eW = enc_W  + (size_t)L * 4 * WSTRIDE;
        const float* eb = enc_b  + (size_t)L * 4 * D_MODEL;
        const float* g  = ln_g   + (size_t)L * 3 * D_MODEL;
        const float* bs = ln_b   + (size_t)L * 3 * D_MODEL;

        // ---- self attention ----
        gemm_bias_kernel<0><<<gp, blk, 0, stream>>>(x, sW + 0 * WSTRIDE, sb + 0 * D_MODEL, bA, M, D_MODEL, D_MODEL);
        gemm_bias_kernel<0><<<gp, blk, 0, stream>>>(x, sW + 1 * WSTRIDE, sb + 1 * D_MODEL, bB, M, D_MODEL, D_MODEL);
        gemm_bias_kernel<0><<<gp, blk, 0, stream>>>(x, sW + 2 * WSTRIDE, sb + 2 * D_MODEL, bC, M, D_MODEL, D_MODEL);
        attn_kernel<<<dim3(nAttnBlk), blk, 0, stream>>>(bA, bB, bC, dec, bD, SEQ, SEQ, 1);
        gemm_bias_kernel<0><<<gp, blk, 0, stream>>>(bD, sW + 3 * WSTRIDE, sb + 3 * D_MODEL, bA, M, D_MODEL, D_MODEL);
        ln_residual_kernel<<<dim3(M / 4), blk, 0, stream>>>(bA, x, g + 0 * D_MODEL, bs + 0 * D_MODEL, x);

        // ---- cross attention (K/V from encoder outputs) ----
        gemm_bias_kernel<0><<<gp, blk, 0, stream>>>(x,       eW + 0 * WSTRIDE, eb + 0 * D_MODEL, bA, M, D_MODEL, D_MODEL);
        gemm_bias_kernel<0><<<gp, blk, 0, stream>>>(enc_out, eW + 1 * WSTRIDE, eb + 1 * D_MODEL, bB, M, D_MODEL, D_MODEL);
        gemm_bias_kernel<0><<<gp, blk, 0, stream>>>(enc_out, eW + 2 * WSTRIDE, eb + 2 * D_MODEL, bC, M, D_MODEL, D_MODEL);
        attn_kernel<<<dim3(nAttnBlk), blk, 0, stream>>>(bA, bB, bC, enc_ids, bD, SEQ, SEQ, 0);
        gemm_bias_kernel<0><<<gp, blk, 0, stream>>>(bD, eW + 3 * WSTRIDE, eb + 3 * D_MODEL, bA, M, D_MODEL, D_MODEL);
        ln_residual_kernel<<<dim3(M / 4), blk, 0, stream>>>(bA, x, g + 1 * D_MODEL, bs + 1 * D_MODEL, x);

        // ---- FFN ----
        gemm_bias_kernel<1><<<gf1, blk, 0, stream>>>(x,  W1 + (size_t)L * D_MODEL * D_FF, b1 + (size_t)L * D_FF,    bH, M, D_FF,    D_MODEL);
        gemm_bias_kernel<0><<<gf2, blk, 0, stream>>>(bH, W2 + (size_t)L * D_FF * D_MODEL, b2 + (size_t)L * D_MODEL, bA, M, D_MODEL, D_FF);
        float* lnout = (L == N_LAYERS - 1) ? out : x;
        ln_residual_kernel<<<dim3(M / 4), blk, 0, stream>>>(bA, x, g + 2 * D_MODEL, bs + 2 * D_MODEL, lnout);
    }
}

// Round 2
// 4071.791 us; speedup vs baseline: 2.0231x; 2.0231x over previous
//
#include <hip/hip_runtime.h>
#include <math.h>

#define D_MODEL 512
#define N_HEADS 8
#define D_KH    64
#define D_FF    2048
#define N_LAYERS 4
#define BSZ     4
#define SEQ     1024

typedef __attribute__((ext_vector_type(8))) __bf16 bf16x8;
typedef __attribute__((ext_vector_type(8))) short  s16x8;
typedef __attribute__((ext_vector_type(4))) float  f32x4;

union BF8 { s16x8 s; bf16x8 b; };

static __device__ inline unsigned short f2b(float f) {
    unsigned u = __float_as_uint(f);
    unsigned r = (u + 0x7fffu + ((u >> 16) & 1u)) >> 16;   // RNE
    return (unsigned short)r;
}

// ---------------- embedding + sinusoid positional encoding ----------------
__global__ void embed_kernel(const int* __restrict__ dec, const float* __restrict__ emb,
                             float* __restrict__ x) {
    int idx = blockIdx.x * blockDim.x + threadIdx.x;  // over BSZ*SEQ*D_MODEL
    int d  = idx % D_MODEL;
    int bs = idx / D_MODEL;
    int s  = bs % SEQ;
    int tok = dec[bs];
    float pos = (float)(s + 5);                        // reference indexes positions 5..S+4
    float e = (float)(d & ~1) / (float)D_MODEL;
    float denom = powf(10000.0f, e);
    float ang = pos / denom;
    float pe = (d & 1) ? cosf(ang) : sinf(ang);
    x[idx] = emb[(size_t)tok * D_MODEL + d] + pe;
}

// ---------------- tiled fp32 GEMM: C[M,N] = A[M,K] @ W[K,N] + bias, optional ReLU -----
template<int RELU>
__global__ void gemm_bias_kernel(const float* __restrict__ A, const float* __restrict__ W,
                                 const float* __restrict__ bias, float* __restrict__ C,
                                 int M, int N, int K) {
    const int BM = 64, BN = 64, BK = 16;
    __shared__ float As[BK][BM + 1];
    __shared__ float Bs[BK][BN + 1];
    int m0 = blockIdx.y * BM;
    int n0 = blockIdx.x * BN;
    int t  = threadIdx.x;           // 256 threads
    int tx = t % 16, ty = t / 16;
    float acc[4][4] = {};
    for (int k0 = 0; k0 < K; k0 += BK) {
        #pragma unroll
        for (int i = 0; i < 4; i++) {            // A tile 64x16
            int lin = t + i * 256;
            int m = lin / BK, k = lin % BK;
            As[k][m] = A[(size_t)(m0 + m) * K + k0 + k];
        }
        #pragma unroll
        for (int i = 0; i < 4; i++) {            // W tile 16x64
            int lin = t + i * 256;
            int k = lin / BN, n = lin % BN;
            Bs[k][n] = W[(size_t)(k0 + k) * N + n0 + n];
        }
        __syncthreads();
        #pragma unroll
        for (int k = 0; k < BK; k++) {
            float a[4], b[4];
            #pragma unroll
            for (int i = 0; i < 4; i++) a[i] = As[k][ty * 4 + i];
            #pragma unroll
            for (int j = 0; j < 4; j++) b[j] = Bs[k][tx * 4 + j];
            #pragma unroll
            for (int i = 0; i < 4; i++)
                #pragma unroll
                for (int j = 0; j < 4; j++)
                    acc[i][j] += a[i] * b[j];
        }
        __syncthreads();
    }
    #pragma unroll
    for (int i = 0; i < 4; i++) {
        int m = m0 + ty * 4 + i;
        #pragma unroll
        for (int j = 0; j < 4; j++) {
            int n = n0 + tx * 4 + j;
            float v = acc[i][j] + bias[n];
            if (RELU) v = fmaxf(v, 0.0f);
            C[(size_t)m * N + n] = v;
        }
    }
}

// ---------------- MFMA bf16 flash attention -------------------------------
// Q/K/V/O: [B, S, H*64], head h at cols h*64..h*64+63 (fp32 in global).
// attend where (ids[b,k]==0) || (causal && k<=q); masked = -1e9 after 0.125 scale.
// Block: 256 thr = 4 waves; QBLK=64 (16 q-rows/wave); KBLK=64.
// MFMA 16x16x32 bf16: A row=lane&15, k=8*(lane>>4)+j (contiguous b128 from row);
// C/D: col=lane&15, row=(lane>>4)*4+reg.
#define RS 72   // padded LDS row length (bf16 elems) = 144B: breaks stride conflicts
__global__ void attn_kernel(const float* __restrict__ Q, const float* __restrict__ K,
                            const float* __restrict__ V, const int* __restrict__ ids,
                            float* __restrict__ O_, int Sq, int Sk, int causal) {
    __shared__ unsigned short Kl[64][RS];      // K rows: [k][d]
    __shared__ unsigned short Vt[64][RS];      // V transposed: [d][k]
    __shared__ unsigned short Ps[4][16][RS];   // per-wave P: [q][k]

    int blk = blockIdx.x;
    int qt = blk % (Sq / 64);
    int bh = blk / (Sq / 64);
    int h = bh % N_HEADS;
    int b = bh / N_HEADS;
    int qbase = qt * 64;
    int t = threadIdx.x;
    int w = t >> 6, lane = t & 63;
    int g = lane >> 4, c = lane & 15;

    // ---- load Q fragments (A-layout: row = c, k = 8*g + j) ----
    BF8 qf[2];
    {
        int qrow = qbase + w * 16 + c;
        const float* qp = Q + ((size_t)(b * Sq + qrow)) * D_MODEL + h * D_KH + 8 * g;
        #pragma unroll
        for (int hh = 0; hh < 2; hh++) {
            float4 f0 = *(const float4*)(qp + 32 * hh);
            float4 f1 = *(const float4*)(qp + 32 * hh + 4);
            qf[hh].s[0] = (short)f2b(f0.x); qf[hh].s[1] = (short)f2b(f0.y);
            qf[hh].s[2] = (short)f2b(f0.z); qf[hh].s[3] = (short)f2b(f0.w);
            qf[hh].s[4] = (short)f2b(f1.x); qf[hh].s[5] = (short)f2b(f1.y);
            qf[hh].s[6] = (short)f2b(f1.z); qf[hh].s[7] = (short)f2b(f1.w);
        }
    }

    float m[4], l[4];
    f32x4 Oacc[4];
    #pragma unroll
    for (int r = 0; r < 4; r++) { m[r] = -INFINITY; l[r] = 0.0f; }
    #pragma unroll
    for (int ds = 0; ds < 4; ds++) Oacc[ds] = (f32x4){0.f, 0.f, 0.f, 0.f};

    for (int k0 = 0; k0 < Sk; k0 += 64) {
        __syncthreads();
        // ---- stage K (rows) and V (transposed), fp32 -> bf16 ----
        #pragma unroll
        for (int i = 0; i < 8; i++) {
            int lin = t + i * 256;            // float2 index over 64x32
            int r = lin >> 5, d2 = lin & 31;
            size_t gaddr = ((size_t)(b * Sk + k0 + r)) * D_MODEL + h * D_KH + 2 * d2;
            float2 kv = *(const float2*)(K + gaddr);
            float2 vv = *(const float2*)(V + gaddr);
            unsigned pk = (unsigned)f2b(kv.x) | ((unsigned)f2b(kv.y) << 16);
            *(unsigned*)&Kl[r][2 * d2] = pk;
            Vt[2 * d2][r]     = f2b(vv.x);
            Vt[2 * d2 + 1][r] = f2b(vv.y);
        }
        __syncthreads();

        // ---- S = Q K^T : 4 k-subtiles x (2 MFMA over d) ----
        f32x4 S[4];
        #pragma unroll
        for (int sub = 0; sub < 4; sub++) {
            BF8 b0, b1;
            b0.b = *(const bf16x8*)&Kl[sub * 16 + c][8 * g];
            b1.b = *(const bf16x8*)&Kl[sub * 16 + c][8 * g + 32];
            f32x4 s = (f32x4){0.f, 0.f, 0.f, 0.f};
            s = __builtin_amdgcn_mfma_f32_16x16x32_bf16(qf[0].b, b0.b, s, 0, 0, 0);
            s = __builtin_amdgcn_mfma_f32_16x16x32_bf16(qf[1].b, b1.b, s, 0, 0, 0);
            S[sub] = s;
        }

        // ---- mask + scale (fp32, post-MFMA) ----
        int idv[4];
        #pragma unroll
        for (int sub = 0; sub < 4; sub++) idv[sub] = ids[b * Sk + k0 + sub * 16 + c];
        #pragma unroll
        for (int sub = 0; sub < 4; sub++) {
            int k = k0 + sub * 16 + c;
            bool pad = (idv[sub] == 0);
            #pragma unroll
            for (int r = 0; r < 4; r++) {
                int qrow = qbase + w * 16 + g * 4 + r;
                bool att = pad || (causal && k <= qrow);
                S[sub][r] = att ? S[sub][r] * 0.125f : -1e9f;
            }
        }

        // ---- online softmax per row (rows live in 16-lane groups) ----
        #pragma unroll
        for (int r = 0; r < 4; r++) {
            float mx = fmaxf(fmaxf(S[0][r], S[1][r]), fmaxf(S[2][r], S[3][r]));
            #pragma unroll
            for (int o = 8; o > 0; o >>= 1) mx = fmaxf(mx, __shfl_xor(mx, o));
            float mn = fmaxf(m[r], mx);
            float sc = expf(m[r] - mn);
            float lsum = 0.f;
            #pragma unroll
            for (int sub = 0; sub < 4; sub++) {
                float p = expf(S[sub][r] - mn);
                S[sub][r] = p;
                lsum += p;
            }
            #pragma unroll
            for (int o = 8; o > 0; o >>= 1) lsum += __shfl_xor(lsum, o);
            l[r] = l[r] * sc + lsum;
            m[r] = mn;
            #pragma unroll
            for (int ds = 0; ds < 4; ds++) Oacc[ds][r] *= sc;
        }

        // ---- P -> LDS (C-layout scatter), bf16 ----
        #pragma unroll
        for (int sub = 0; sub < 4; sub++)
            #pragma unroll
            for (int r = 0; r < 4; r++)
                Ps[w][g * 4 + r][sub * 16 + c] = f2b(S[sub][r]);

        // ---- O += P V  (A from Ps rows, B from Vt rows) ----
        #pragma unroll
        for (int kk = 0; kk < 2; kk++) {
            BF8 pa;
            pa.b = *(const bf16x8*)&Ps[w][c][8 * g + kk * 32];
            #pragma unroll
            for (int ds = 0; ds < 4; ds++) {
                BF8 vb;
                vb.b = *(const bf16x8*)&Vt[ds * 16 + c][8 * g + kk * 32];
                Oacc[ds] = __builtin_amdgcn_mfma_f32_16x16x32_bf16(pa.b, vb.b, Oacc[ds], 0, 0, 0);
            }
        }
    }

    // ---- epilogue: O / l ----
    #pragma unroll
    for (int r = 0; r < 4; r++) {
        float inv = 1.0f / l[r];
        int qrow = qbase + w * 16 + g * 4 + r;
        float* op = O_ + ((size_t)(b * Sq + qrow)) * D_MODEL + h * D_KH;
        #pragma unroll
        for (int ds = 0; ds < 4; ds++)
            op[ds * 16 + c] = Oacc[ds][r] * inv;
    }
}

// ---------------- layernorm(f + h) with gain/bias, one wave per 512-row -------------
__global__ void ln_residual_kernel(const float* __restrict__ f, const float* __restrict__ h,
                                   const float* __restrict__ g, const float* __restrict__ bb,
                                   float* __restrict__ out) {
    int row  = blockIdx.x * 4 + threadIdx.x / 64;
    int lane = threadIdx.x % 64;
    const float* fr = f + (size_t)row * D_MODEL;
    const float* hr = h + (size_t)row * D_MODEL;
    float v[8];
    float s = 0.f;
    #pragma unroll
    for (int i = 0; i < 8; i++) {
        v[i] = fr[lane + i * 64] + hr[lane + i * 64];
        s += v[i];
    }
    #pragma unroll
    for (int o = 32; o > 0; o >>= 1) s += __shfl_xor(s, o);
    float mu = s * (1.0f / 512.0f);
    float ss = 0.f;
    #pragma unroll
    for (int i = 0; i < 8; i++) { float d = v[i] - mu; ss += d * d; }
    #pragma unroll
    for (int o = 32; o > 0; o >>= 1) ss += __shfl_xor(ss, o);
    float var = ss * (1.0f / 512.0f);
    float inv = 1.0f / sqrtf(var + 1e-6f);
    #pragma unroll
    for (int i = 0; i < 8; i++) {
        int d = lane + i * 64;
        out[(size_t)row * D_MODEL + d] = g[d] * (v[i] - mu) * inv + bb[d];
    }
}

extern "C" void kernel_launch(void* const* d_in, const int* in_sizes, int n_in,
                              void* d_out, int out_size, void* d_ws, size_t ws_size,
                              hipStream_t stream) {
    const int*   dec     = (const int*)d_in[0];
    const int*   enc_ids = (const int*)d_in[1];
    const float* enc_out = (const float*)d_in[2];
    const float* emb     = (const float*)d_in[3];
    const float* self_W  = (const float*)d_in[4];
    const float* self_b  = (const float*)d_in[5];
    const float* enc_W   = (const float*)d_in[6];
    const float* enc_b   = (const float*)d_in[7];
    const float* W1      = (const float*)d_in[8];
    const float* b1      = (const float*)d_in[9];
    const float* W2      = (const float*)d_in[10];
    const float* b2      = (const float*)d_in[11];
    const float* ln_g    = (const float*)d_in[12];
    const float* ln_b    = (const float*)d_in[13];
    float* out = (float*)d_out;

    const size_t NTOK = (size_t)BSZ * SEQ;      // 4096
    float* x   = (float*)d_ws;
    float* bA  = x + NTOK * D_MODEL;
    float* reg = bA + NTOK * D_MODEL;
    float* bB  = reg;
    float* bC  = reg + NTOK * D_MODEL;
    float* bD  = reg + 2 * NTOK * D_MODEL;
    float* bH  = reg;                            // NTOK * D_FF, reused after attention

    dim3 blk(256);
    embed_kernel<<<dim3((unsigned)(NTOK * D_MODEL / 256)), blk, 0, stream>>>(dec, emb, x);

    int M = (int)NTOK;
    dim3 gp (D_MODEL / 64, M / 64);
    dim3 gf1(D_FF   / 64, M / 64);
    dim3 gf2(D_MODEL / 64, M / 64);
    int nAttnBlk = BSZ * N_HEADS * (SEQ / 64);

    const size_t WSTRIDE = (size_t)D_MODEL * D_MODEL;
    for (int L = 0; L < N_LAYERS; L++) {
        const float* sW = self_W + (size_t)L * 4 * WSTRIDE;
        const float* sb = self_b + (size_t)L * 4 * D_MODEL;
        const float* eW = enc_W  + (size_t)L * 4 * WSTRIDE;
        const float* eb = enc_b  + (size_t)L * 4 * D_MODEL;
        const float* g  = ln_g   + (size_t)L * 3 * D_MODEL;
        const float* bs = ln_b   + (size_t)L * 3 * D_MODEL;

        // ---- self attention ----
        gemm_bias_kernel<0><<<gp, blk, 0, stream>>>(x, sW + 0 * WSTRIDE, sb + 0 * D_MODEL, bA, M, D_MODEL, D_MODEL);
        gemm_bias_kernel<0><<<gp, blk, 0, stream>>>(x, sW + 1 * WSTRIDE, sb + 1 * D_MODEL, bB, M, D_MODEL, D_MODEL);
        gemm_bias_kernel<0><<<gp, blk, 0, stream>>>(x, sW + 2 * WSTRIDE, sb + 2 * D_MODEL, bC, M, D_MODEL, D_MODEL);
        attn_kernel<<<dim3(nAttnBlk), blk, 0, stream>>>(bA, bB, bC, dec, bD, SEQ, SEQ, 1);
        gemm_bias_kernel<0><<<gp, blk, 0, stream>>>(bD, sW + 3 * WSTRIDE, sb + 3 * D_MODEL, bA, M, D_MODEL, D_MODEL);
        ln_residual_kernel<<<dim3(M / 4), blk, 0, stream>>>(bA, x, g + 0 * D_MODEL, bs + 0 * D_MODEL, x);

        // ---- cross attention (K/V from encoder outputs) ----
        gemm_bias_kernel<0><<<gp, blk, 0, stream>>>(x,       eW + 0 * WSTRIDE, eb + 0 * D_MODEL, bA, M, D_MODEL, D_MODEL);
        gemm_bias_kernel<0><<<gp, blk, 0, stream>>>(enc_out, eW + 1 * WSTRIDE, eb + 1 * D_MODEL, bB, M, D_MODEL, D_MODEL);
        gemm_bias_kernel<0><<<gp, blk, 0, stream>>>(enc_out, eW + 2 * WSTRIDE, eb + 2 * D_MODEL, bC, M, D_MODEL, D_MODEL);
        attn_kernel<<<dim3(nAttnBlk), blk, 0, stream>>>(bA, bB, bC, enc_ids, bD, SEQ, SEQ, 0);
        gemm_bias_kernel<0><<<gp, blk, 0, stream>>>(bD, eW + 3 * WSTRIDE, eb + 3 * D_MODEL, bA, M, D_MODEL, D_MODEL);
        ln_residual_kernel<<<dim3(M / 4), blk, 0, stream>>>(bA, x, g + 1 * D_MODEL, bs + 1 * D_MODEL, x);

        // ---- FFN ----
        gemm_bias_kernel<1><<<gf1, blk, 0, stream>>>(x,  W1 + (size_t)L * D_MODEL * D_FF, b1 + (size_t)L * D_FF,    bH, M, D_FF,    D_MODEL);
        gemm_bias_kernel<0><<<gf2, blk, 0, stream>>>(bH, W2 + (size_t)L * D_FF * D_MODEL, b2 + (size_t)L * D_MODEL, bA, M, D_MODEL, D_FF);
        float* lnout = (L == N_LAYERS - 1) ? out : x;
        ln_residual_kernel<<<dim3(M / 4), blk, 0, stream>>>(bA, x, g + 2 * D_MODEL, bs + 2 * D_MODEL, lnout);
    }
}

// Round 3
// 2851.613 us; speedup vs baseline: 2.8887x; 1.4279x over previous
//
#include <hip/hip_runtime.h>
#include <math.h>

#define D_MODEL 512
#define N_HEADS 8
#define D_KH    64
#define D_FF    2048
#define N_LAYERS 4
#define BSZ     4
#define SEQ     1024

typedef __attribute__((ext_vector_type(8))) __bf16 bf16x8;
typedef __attribute__((ext_vector_type(8))) short  s16x8;
typedef __attribute__((ext_vector_type(4))) float  f32x4;

union BF8 { s16x8 s; bf16x8 b; };

static __device__ inline unsigned short f2b(float f) {
    unsigned u = __float_as_uint(f);
    unsigned r = (u + 0x7fffu + ((u >> 16) & 1u)) >> 16;   // RNE
    return (unsigned short)r;
}

// ---------------- embedding + sinusoid positional encoding ----------------
__global__ void embed_kernel(const int* __restrict__ dec, const float* __restrict__ emb,
                             float* __restrict__ x) {
    int idx = blockIdx.x * blockDim.x + threadIdx.x;  // over BSZ*SEQ*D_MODEL
    int d  = idx % D_MODEL;
    int bs = idx / D_MODEL;
    int s  = bs % SEQ;
    int tok = dec[bs];
    float pos = (float)(s + 5);                        // reference indexes positions 5..S+4
    float e = (float)(d & ~1) / (float)D_MODEL;
    float denom = powf(10000.0f, e);
    float ang = pos / denom;
    float pe = (d & 1) ? cosf(ang) : sinf(ang);
    x[idx] = emb[(size_t)tok * D_MODEL + d] + pe;
}

// ---------------- bf16 MFMA GEMM: C[M,N] = A[M,K] @ W[K,N] + bias --------------------
// BM=128, BN=64, BK=32; 256 thr = 4 waves (2x2), each wave 64x32 = 4x2 frags 16x16.
// A staged [128][40] bf16 (pad->80B row stride: b128 frag reads 2-way = free).
// W staged transposed [64][40] bf16 (B-fragment needs contiguous K).
// ABF16: A is bf16 (else fp32, converted in staging). OUTBF16: emit bf16 (else fp32).
template<int ABF16, int OUTBF16, int RELU>
__global__ void gemm_mfma_kernel(const void* __restrict__ A_, const float* __restrict__ W,
                                 const float* __restrict__ bias, void* __restrict__ C_,
                                 int M, int N, int K) {
    __shared__ unsigned short As[128][40];
    __shared__ unsigned short Ws[64][40];
    int m0 = blockIdx.y * 128, n0 = blockIdx.x * 64;
    int t = threadIdx.x;
    int w = t >> 6, lane = t & 63;
    int wm = w >> 1, wn = w & 1;
    int g = lane >> 4, c = lane & 15;

    f32x4 acc[4][2];
    #pragma unroll
    for (int mi = 0; mi < 4; mi++)
        #pragma unroll
        for (int nj = 0; nj < 2; nj++) acc[mi][nj] = (f32x4){0.f, 0.f, 0.f, 0.f};

    for (int k0 = 0; k0 < K; k0 += 32) {
        if (ABF16) {
            const unsigned short* Ab = (const unsigned short*)A_;
            #pragma unroll
            for (int i = 0; i < 2; i++) {
                int idx = t + i * 256;             // 128 rows x 4 slots of 8 bf16
                int r = idx >> 2, s = idx & 3;
                *(s16x8*)&As[r][s * 8] = *(const s16x8*)(Ab + (size_t)(m0 + r) * K + k0 + s * 8);
            }
        } else {
            const float* Af = (const float*)A_;
            #pragma unroll
            for (int i = 0; i < 4; i++) {
                int idx = t + i * 256;             // 128 rows x 8 float4 slots
                int r = idx >> 3, s = idx & 7;
                float4 f = *(const float4*)(Af + (size_t)(m0 + r) * K + k0 + s * 4);
                ushort4 h;
                h.x = f2b(f.x); h.y = f2b(f.y); h.z = f2b(f.z); h.w = f2b(f.w);
                *(ushort4*)&As[r][s * 4] = h;
            }
        }
        // W tile [32][64] fp32 -> Ws[n][k] bf16 (transposed)
        #pragma unroll
        for (int i = 0; i < 4; i++) {
            int idx = t + i * 256;                 // 32 k-rows x 32 float2 slots
            int kk = idx >> 5, n2 = idx & 31;
            float2 f = *(const float2*)(W + (size_t)(k0 + kk) * N + n0 + n2 * 2);
            Ws[n2 * 2][kk]     = f2b(f.x);
            Ws[n2 * 2 + 1][kk] = f2b(f.y);
        }
        __syncthreads();
        BF8 a[4], b[2];
        #pragma unroll
        for (int mi = 0; mi < 4; mi++) a[mi].b = *(const bf16x8*)&As[wm * 64 + mi * 16 + c][8 * g];
        #pragma unroll
        for (int nj = 0; nj < 2; nj++) b[nj].b = *(const bf16x8*)&Ws[wn * 32 + nj * 16 + c][8 * g];
        #pragma unroll
        for (int mi = 0; mi < 4; mi++)
            #pragma unroll
            for (int nj = 0; nj < 2; nj++)
                acc[mi][nj] = __builtin_amdgcn_mfma_f32_16x16x32_bf16(a[mi].b, b[nj].b, acc[mi][nj], 0, 0, 0);
        __syncthreads();
    }
    #pragma unroll
    for (int mi = 0; mi < 4; mi++) {
        #pragma unroll
        for (int nj = 0; nj < 2; nj++) {
            #pragma unroll
            for (int r = 0; r < 4; r++) {
                int row = m0 + wm * 64 + mi * 16 + g * 4 + r;
                int col = n0 + wn * 32 + nj * 16 + c;
                float v = acc[mi][nj][r] + bias[col];
                if (RELU) v = fmaxf(v, 0.0f);
                if (OUTBF16) ((unsigned short*)C_)[(size_t)row * N + col] = f2b(v);
                else         ((float*)C_)[(size_t)row * N + col] = v;
            }
        }
    }
}

// ---------------- MFMA bf16 flash attention (bf16 in / bf16 out) -------------------
// Q/K/V/O: [B, S, H*64] bf16, head h at cols h*64..h*64+63.
// attend where (ids[b,k]==0) || (causal && k<=q); masked = -1e9 after 0.125 scale.
#define RS 72
__global__ void attn_kernel(const unsigned short* __restrict__ Q, const unsigned short* __restrict__ K,
                            const unsigned short* __restrict__ V, const int* __restrict__ ids,
                            unsigned short* __restrict__ O_, int Sq, int Sk, int causal) {
    __shared__ unsigned short Kl[64][RS];      // K rows: [k][d]
    __shared__ unsigned short Vt[64][RS];      // V transposed: [d][k]
    __shared__ unsigned short Ps[4][16][RS];   // per-wave P: [q][k]

    int blk = blockIdx.x;
    int qt = blk % (Sq / 64);
    int bh = blk / (Sq / 64);
    int h = bh % N_HEADS;
    int b = bh / N_HEADS;
    int qbase = qt * 64;
    int t = threadIdx.x;
    int w = t >> 6, lane = t & 63;
    int g = lane >> 4, c = lane & 15;

    BF8 qf[2];
    {
        int qrow = qbase + w * 16 + c;
        const unsigned short* qp = Q + ((size_t)(b * Sq + qrow)) * D_MODEL + h * D_KH;
        qf[0].s = *(const s16x8*)(qp + 8 * g);
        qf[1].s = *(const s16x8*)(qp + 8 * g + 32);
    }

    float m[4], l[4];
    f32x4 Oacc[4];
    #pragma unroll
    for (int r = 0; r < 4; r++) { m[r] = -INFINITY; l[r] = 0.0f; }
    #pragma unroll
    for (int ds = 0; ds < 4; ds++) Oacc[ds] = (f32x4){0.f, 0.f, 0.f, 0.f};

    for (int k0 = 0; k0 < Sk; k0 += 64) {
        __syncthreads();
        #pragma unroll
        for (int i = 0; i < 2; i++) {
            int lin = t + i * 256;             // 64 rows x 8 slots of 8 bf16
            int r = lin >> 3, s = lin & 7;
            size_t gaddr = ((size_t)(b * Sk + k0 + r)) * D_MODEL + h * D_KH + s * 8;
            *(s16x8*)&Kl[r][s * 8] = *(const s16x8*)(K + gaddr);
            s16x8 vv = *(const s16x8*)(V + gaddr);
            #pragma unroll
            for (int j = 0; j < 8; j++) Vt[s * 8 + j][r] = ((unsigned short*)&vv)[j];
        }
        __syncthreads();

        f32x4 S[4];
        #pragma unroll
        for (int sub = 0; sub < 4; sub++) {
            BF8 b0, b1;
            b0.s = *(const s16x8*)&Kl[sub * 16 + c][8 * g];
            b1.s = *(const s16x8*)&Kl[sub * 16 + c][8 * g + 32];
            f32x4 s = (f32x4){0.f, 0.f, 0.f, 0.f};
            s = __builtin_amdgcn_mfma_f32_16x16x32_bf16(qf[0].b, b0.b, s, 0, 0, 0);
            s = __builtin_amdgcn_mfma_f32_16x16x32_bf16(qf[1].b, b1.b, s, 0, 0, 0);
            S[sub] = s;
        }

        int idv[4];
        #pragma unroll
        for (int sub = 0; sub < 4; sub++) idv[sub] = ids[b * Sk + k0 + sub * 16 + c];
        #pragma unroll
        for (int sub = 0; sub < 4; sub++) {
            int k = k0 + sub * 16 + c;
            bool pad = (idv[sub] == 0);
            #pragma unroll
            for (int r = 0; r < 4; r++) {
                int qrow = qbase + w * 16 + g * 4 + r;
                bool att = pad || (causal && k <= qrow);
                S[sub][r] = att ? S[sub][r] * 0.125f : -1e9f;
            }
        }

        #pragma unroll
        for (int r = 0; r < 4; r++) {
            float mx = fmaxf(fmaxf(S[0][r], S[1][r]), fmaxf(S[2][r], S[3][r]));
            #pragma unroll
            for (int o = 8; o > 0; o >>= 1) mx = fmaxf(mx, __shfl_xor(mx, o));
            float mn = fmaxf(m[r], mx);
            float sc = expf(m[r] - mn);
            float lsum = 0.f;
            #pragma unroll
            for (int sub = 0; sub < 4; sub++) {
                float p = expf(S[sub][r] - mn);
                S[sub][r] = p;
                lsum += p;
            }
            #pragma unroll
            for (int o = 8; o > 0; o >>= 1) lsum += __shfl_xor(lsum, o);
            l[r] = l[r] * sc + lsum;
            m[r] = mn;
            #pragma unroll
            for (int ds = 0; ds < 4; ds++) Oacc[ds][r] *= sc;
        }

        #pragma unroll
        for (int sub = 0; sub < 4; sub++)
            #pragma unroll
            for (int r = 0; r < 4; r++)
                Ps[w][g * 4 + r][sub * 16 + c] = f2b(S[sub][r]);

        #pragma unroll
        for (int kk = 0; kk < 2; kk++) {
            BF8 pa;
            pa.s = *(const s16x8*)&Ps[w][c][8 * g + kk * 32];
            #pragma unroll
            for (int ds = 0; ds < 4; ds++) {
                BF8 vb;
                vb.s = *(const s16x8*)&Vt[ds * 16 + c][8 * g + kk * 32];
                Oacc[ds] = __builtin_amdgcn_mfma_f32_16x16x32_bf16(pa.b, vb.b, Oacc[ds], 0, 0, 0);
            }
        }
    }

    #pragma unroll
    for (int r = 0; r < 4; r++) {
        float inv = 1.0f / l[r];
        int qrow = qbase + w * 16 + g * 4 + r;
        unsigned short* op = O_ + ((size_t)(b * Sq + qrow)) * D_MODEL + h * D_KH;
        #pragma unroll
        for (int ds = 0; ds < 4; ds++)
            op[ds * 16 + c] = f2b(Oacc[ds][r] * inv);
    }
}

// ---------------- layernorm(f + h) with gain/bias, one wave per 512-row -------------
__global__ void ln_residual_kernel(const float* __restrict__ f, const float* __restrict__ h,
                                   const float* __restrict__ g, const float* __restrict__ bb,
                                   float* __restrict__ out) {
    int row  = blockIdx.x * 4 + threadIdx.x / 64;
    int lane = threadIdx.x % 64;
    const float* fr = f + (size_t)row * D_MODEL;
    const float* hr = h + (size_t)row * D_MODEL;
    float v[8];
    float s = 0.f;
    #pragma unroll
    for (int i = 0; i < 8; i++) {
        v[i] = fr[lane + i * 64] + hr[lane + i * 64];
        s += v[i];
    }
    #pragma unroll
    for (int o = 32; o > 0; o >>= 1) s += __shfl_xor(s, o);
    float mu = s * (1.0f / 512.0f);
    float ss = 0.f;
    #pragma unroll
    for (int i = 0; i < 8; i++) { float d = v[i] - mu; ss += d * d; }
    #pragma unroll
    for (int o = 32; o > 0; o >>= 1) ss += __shfl_xor(ss, o);
    float var = ss * (1.0f / 512.0f);
    float inv = 1.0f / sqrtf(var + 1e-6f);
    #pragma unroll
    for (int i = 0; i < 8; i++) {
        int d = lane + i * 64;
        out[(size_t)row * D_MODEL + d] = g[d] * (v[i] - mu) * inv + bb[d];
    }
}

extern "C" void kernel_launch(void* const* d_in, const int* in_sizes, int n_in,
                              void* d_out, int out_size, void* d_ws, size_t ws_size,
                              hipStream_t stream) {
    const int*   dec     = (const int*)d_in[0];
    const int*   enc_ids = (const int*)d_in[1];
    const float* enc_out = (const float*)d_in[2];
    const float* emb     = (const float*)d_in[3];
    const float* self_W  = (const float*)d_in[4];
    const float* self_b  = (const float*)d_in[5];
    const float* enc_W   = (const float*)d_in[6];
    const float* enc_b   = (const float*)d_in[7];
    const float* W1      = (const float*)d_in[8];
    const float* b1      = (const float*)d_in[9];
    const float* W2      = (const float*)d_in[10];
    const float* b2      = (const float*)d_in[11];
    const float* ln_g    = (const float*)d_in[12];
    const float* ln_b    = (const float*)d_in[13];
    float* out = (float*)d_out;

    const size_t NTOK = (size_t)BSZ * SEQ;      // 4096
    // ws: x(8MB f32) + bA(8MB f32) + 16MB bf16 region {bQ,bK,bV,bD} / {bH}
    float* x  = (float*)d_ws;
    float* bA = x + NTOK * D_MODEL;
    unsigned short* bQ = (unsigned short*)(bA + NTOK * D_MODEL);
    unsigned short* bK = bQ + NTOK * D_MODEL;
    unsigned short* bV = bK + NTOK * D_MODEL;
    unsigned short* bD = bV + NTOK * D_MODEL;
    unsigned short* bH = bQ;                    // 4096*2048 bf16 = 16MB, aliases bQ..bD

    dim3 blk(256);
    embed_kernel<<<dim3((unsigned)(NTOK * D_MODEL / 256)), blk, 0, stream>>>(dec, emb, x);

    int M = (int)NTOK;
    dim3 gp (D_MODEL / 64, M / 128);   // proj: 8 x 32
    dim3 gf1(D_FF   / 64, M / 128);    // FFN1: 32 x 32
    dim3 gf2(D_MODEL / 64, M / 128);   // FFN2: 8 x 32
    int nAttnBlk = BSZ * N_HEADS * (SEQ / 64);

    const size_t WSTRIDE = (size_t)D_MODEL * D_MODEL;
    for (int L = 0; L < N_LAYERS; L++) {
        const float* sW = self_W + (size_t)L * 4 * WSTRIDE;
        const float* sb = self_b + (size_t)L * 4 * D_MODEL;
        const float* eW = enc_W  + (size_t)L * 4 * WSTRIDE;
        const float* eb = enc_b  + (size_t)L * 4 * D_MODEL;
        const float* g  = ln_g   + (size_t)L * 3 * D_MODEL;
        const float* bs = ln_b   + (size_t)L * 3 * D_MODEL;

        // ---- self attention ----
        gemm_mfma_kernel<0,1,0><<<gp, blk, 0, stream>>>(x, sW + 0 * WSTRIDE, sb + 0 * D_MODEL, bQ, M, D_MODEL, D_MODEL);
        gemm_mfma_kernel<0,1,0><<<gp, blk, 0, stream>>>(x, sW + 1 * WSTRIDE, sb + 1 * D_MODEL, bK, M, D_MODEL, D_MODEL);
        gemm_mfma_kernel<0,1,0><<<gp, blk, 0, stream>>>(x, sW + 2 * WSTRIDE, sb + 2 * D_MODEL, bV, M, D_MODEL, D_MODEL);
        attn_kernel<<<dim3(nAttnBlk), blk, 0, stream>>>(bQ, bK, bV, dec, bD, SEQ, SEQ, 1);
        gemm_mfma_kernel<1,0,0><<<gp, blk, 0, stream>>>(bD, sW + 3 * WSTRIDE, sb + 3 * D_MODEL, bA, M, D_MODEL, D_MODEL);
        ln_residual_kernel<<<dim3(M / 4), blk, 0, stream>>>(bA, x, g + 0 * D_MODEL, bs + 0 * D_MODEL, x);

        // ---- cross attention (K/V from encoder outputs) ----
        gemm_mfma_kernel<0,1,0><<<gp, blk, 0, stream>>>(x,       eW + 0 * WSTRIDE, eb + 0 * D_MODEL, bQ, M, D_MODEL, D_MODEL);
        gemm_mfma_kernel<0,1,0><<<gp, blk, 0, stream>>>(enc_out, eW + 1 * WSTRIDE, eb + 1 * D_MODEL, bK, M, D_MODEL, D_MODEL);
        gemm_mfma_kernel<0,1,0><<<gp, blk, 0, stream>>>(enc_out, eW + 2 * WSTRIDE, eb + 2 * D_MODEL, bV, M, D_MODEL, D_MODEL);
        attn_kernel<<<dim3(nAttnBlk), blk, 0, stream>>>(bQ, bK, bV, enc_ids, bD, SEQ, SEQ, 0);
        gemm_mfma_kernel<1,0,0><<<gp, blk, 0, stream>>>(bD, eW + 3 * WSTRIDE, eb + 3 * D_MODEL, bA, M, D_MODEL, D_MODEL);
        ln_residual_kernel<<<dim3(M / 4), blk, 0, stream>>>(bA, x, g + 1 * D_MODEL, bs + 1 * D_MODEL, x);

        // ---- FFN ----
        gemm_mfma_kernel<0,1,1><<<gf1, blk, 0, stream>>>(x,  W1 + (size_t)L * D_MODEL * D_FF, b1 + (size_t)L * D_FF,    bH, M, D_FF,    D_MODEL);
        gemm_mfma_kernel<1,0,0><<<gf2, blk, 0, stream>>>(bH, W2 + (size_t)L * D_FF * D_MODEL, b2 + (size_t)L * D_MODEL, bA, M, D_MODEL, D_FF);
        float* lnout = (L == N_LAYERS - 1) ? out : x;
        ln_residual_kernel<<<dim3(M / 4), blk, 0, stream>>>(bA, x, g + 2 * D_MODEL, bs + 2 * D_MODEL, lnout);
    }
}

// Round 4
// 1305.323 us; speedup vs baseline: 6.3108x; 2.1846x over previous
//
#include <hip/hip_runtime.h>
#include <math.h>

#define D_MODEL 512
#define N_HEADS 8
#define D_KH    64
#define D_FF    2048
#define N_LAYERS 4
#define BSZ     4
#define SEQ     1024

typedef __attribute__((ext_vector_type(8))) __bf16 bf16x8;
typedef __attribute__((ext_vector_type(8))) short  s16x8;
typedef __attribute__((ext_vector_type(4))) float  f32x4;

union BF8 { s16x8 s; bf16x8 b; };

static __device__ inline unsigned short f2b(float f) {
    unsigned u = __float_as_uint(f);
    unsigned r = (u + 0x7fffu + ((u >> 16) & 1u)) >> 16;   // RNE
    return (unsigned short)r;
}

// ---------------- embedding + sinusoid positional encoding (fp32 + bf16 shadow) -----
__global__ void embed_kernel(const int* __restrict__ dec, const float* __restrict__ emb,
                             float* __restrict__ x, unsigned short* __restrict__ xb) {
    int idx = blockIdx.x * blockDim.x + threadIdx.x;  // over BSZ*SEQ*D_MODEL
    int d  = idx % D_MODEL;
    int bs = idx / D_MODEL;
    int s  = bs % SEQ;
    int tok = dec[bs];
    float pos = (float)(s + 5);                        // reference indexes positions 5..S+4
    float e = (float)(d & ~1) / (float)D_MODEL;
    float denom = powf(10000.0f, e);
    float ang = pos / denom;
    float pe = (d & 1) ? cosf(ang) : sinf(ang);
    float v = emb[(size_t)tok * D_MODEL + d] + pe;
    x[idx] = v;
    xb[idx] = f2b(v);
}

// ---------------- fp32 -> bf16 bulk convert (enc_out, once) -------------------------
__global__ void cvt_bf16_kernel(const float* __restrict__ in, unsigned short* __restrict__ outp, int n4) {
    int i = blockIdx.x * blockDim.x + threadIdx.x;
    if (i < n4) {
        float4 f = ((const float4*)in)[i];
        ushort4 h;
        h.x = f2b(f.x); h.y = f2b(f.y); h.z = f2b(f.z); h.w = f2b(f.w);
        ((ushort4*)outp)[i] = h;
    }
}

// ---------------- bf16 MFMA GEMM, double-buffered, reg-prefetched -------------------
// C[M,N] = A[M,K](bf16) @ W[K,N](fp32) + bias.  BM=BN=BK=64, 4 waves (2x2), each wave
// 32x32 out = 2x2 frags, 8 MFMA per k-tile.  LDS rows padded to 72 (144B: b128 frag
// reads 2-way = free).  W transposed during store as 2k x 2n b32 packs (4-way).
// Pipeline: issue next-tile global loads -> barrier -> ds_read+MFMA -> cvt+ds_write.
template<int OUTBF16, int RELU>
__launch_bounds__(256, 4)
__global__ void gemm_mfma_kernel(const unsigned short* __restrict__ A, const float* __restrict__ W,
                                 const float* __restrict__ bias, void* __restrict__ C_,
                                 int M, int N, int K) {
    __shared__ unsigned short As[2][64][72];
    __shared__ unsigned short Ws[2][64][72];
    int m0 = blockIdx.x * 64, n0 = blockIdx.y * 64;   // x fastest: neighbors share W panel
    int t = threadIdx.x;
    int w = t >> 6, lane = t & 63;
    int wm = w >> 1, wn = w & 1;
    int g = lane >> 4, c = lane & 15;

    // staging assignments (compile-time unrolled, static reg indexing)
    int ar0 = t >> 3,            as0 = t & 7;          // A slots: 64 rows x 8 x (8 bf16)
    int ar1 = (t + 256) >> 3,    as1 = (t + 256) & 7;
    int ukp[4], unp[4];                                // W units: 32 kpairs x 32 npairs
    #pragma unroll
    for (int p = 0; p < 4; p++) { int u = t + p * 256; ukp[p] = u >> 5; unp[p] = u & 31; }

    s16x8  aReg0, aReg1;
    float2 wReg[4][2];

    f32x4 acc[2][2];
    #pragma unroll
    for (int mi = 0; mi < 2; mi++)
        #pragma unroll
        for (int nj = 0; nj < 2; nj++) acc[mi][nj] = (f32x4){0.f, 0.f, 0.f, 0.f};

#define ISSUE_LOADS(KT) do {                                                         \
        int k0_ = (KT) * 64;                                                         \
        aReg0 = *(const s16x8*)(A + (size_t)(m0 + ar0) * K + k0_ + as0 * 8);         \
        aReg1 = *(const s16x8*)(A + (size_t)(m0 + ar1) * K + k0_ + as1 * 8);         \
        _Pragma("unroll")                                                            \
        for (int p = 0; p < 4; p++) {                                                \
            int k_ = k0_ + ukp[p] * 2, n_ = n0 + unp[p] * 2;                         \
            wReg[p][0] = *(const float2*)(W + (size_t)k_ * N + n_);                  \
            wReg[p][1] = *(const float2*)(W + (size_t)(k_ + 1) * N + n_);            \
        }                                                                            \
    } while (0)

#define STORE_LDS(B) do {                                                            \
        *(s16x8*)&As[B][ar0][as0 * 8] = aReg0;                                       \
        *(s16x8*)&As[B][ar1][as1 * 8] = aReg1;                                       \
        _Pragma("unroll")                                                            \
        for (int p = 0; p < 4; p++) {                                                \
            unsigned lo = (unsigned)f2b(wReg[p][0].x) | ((unsigned)f2b(wReg[p][1].x) << 16); \
            unsigned hi = (unsigned)f2b(wReg[p][0].y) | ((unsigned)f2b(wReg[p][1].y) << 16); \
            *(unsigned*)&Ws[B][unp[p] * 2    ][ukp[p] * 2] = lo;                     \
            *(unsigned*)&Ws[B][unp[p] * 2 + 1][ukp[p] * 2] = hi;                     \
        }                                                                            \
    } while (0)

    int nt = K >> 6;
    ISSUE_LOADS(0);
    STORE_LDS(0);
    for (int kt = 0; kt < nt; ++kt) {
        int cur = kt & 1;
        if (kt + 1 < nt) ISSUE_LOADS(kt + 1);
        __syncthreads();
        BF8 a[2][2], b[2][2];
        #pragma unroll
        for (int kk = 0; kk < 2; kk++) {
            #pragma unroll
            for (int mi = 0; mi < 2; mi++)
                a[kk][mi].s = *(const s16x8*)&As[cur][wm * 32 + mi * 16 + c][kk * 32 + 8 * g];
            #pragma unroll
            for (int nj = 0; nj < 2; nj++)
                b[kk][nj].s = *(const s16x8*)&Ws[cur][wn * 32 + nj * 16 + c][kk * 32 + 8 * g];
        }
        #pragma unroll
        for (int kk = 0; kk < 2; kk++)
            #pragma unroll
            for (int mi = 0; mi < 2; mi++)
                #pragma unroll
                for (int nj = 0; nj < 2; nj++)
                    acc[mi][nj] = __builtin_amdgcn_mfma_f32_16x16x32_bf16(a[kk][mi].b, b[kk][nj].b, acc[mi][nj], 0, 0, 0);
        if (kt + 1 < nt) STORE_LDS((kt + 1) & 1);
    }
#undef ISSUE_LOADS
#undef STORE_LDS

    #pragma unroll
    for (int mi = 0; mi < 2; mi++) {
        #pragma unroll
        for (int nj = 0; nj < 2; nj++) {
            #pragma unroll
            for (int r = 0; r < 4; r++) {
                int row = m0 + wm * 32 + mi * 16 + g * 4 + r;
                int col = n0 + wn * 32 + nj * 16 + c;
                float v = acc[mi][nj][r] + bias[col];
                if (RELU) v = fmaxf(v, 0.0f);
                if (OUTBF16) ((unsigned short*)C_)[(size_t)row * N + col] = f2b(v);
                else         ((float*)C_)[(size_t)row * N + col] = v;
            }
        }
    }
}

// ---------------- MFMA bf16 flash attention (bf16 in / bf16 out) -------------------
#define RS 72
__global__ void attn_kernel(const unsigned short* __restrict__ Q, const unsigned short* __restrict__ K,
                            const unsigned short* __restrict__ V, const int* __restrict__ ids,
                            unsigned short* __restrict__ O_, int Sq, int Sk, int causal) {
    __shared__ unsigned short Kl[64][RS];      // K rows: [k][d]
    __shared__ unsigned short Vt[64][RS];      // V transposed: [d][k]
    __shared__ unsigned short Ps[4][16][RS];   // per-wave P: [q][k]

    int blk = blockIdx.x;
    int qt = blk % (Sq / 64);
    int bh = blk / (Sq / 64);
    int h = bh % N_HEADS;
    int b = bh / N_HEADS;
    int qbase = qt * 64;
    int t = threadIdx.x;
    int w = t >> 6, lane = t & 63;
    int g = lane >> 4, c = lane & 15;

    BF8 qf[2];
    {
        int qrow = qbase + w * 16 + c;
        const unsigned short* qp = Q + ((size_t)(b * Sq + qrow)) * D_MODEL + h * D_KH;
        qf[0].s = *(const s16x8*)(qp + 8 * g);
        qf[1].s = *(const s16x8*)(qp + 8 * g + 32);
    }

    float m[4], l[4];
    f32x4 Oacc[4];
    #pragma unroll
    for (int r = 0; r < 4; r++) { m[r] = -INFINITY; l[r] = 0.0f; }
    #pragma unroll
    for (int ds = 0; ds < 4; ds++) Oacc[ds] = (f32x4){0.f, 0.f, 0.f, 0.f};

    for (int k0 = 0; k0 < Sk; k0 += 64) {
        __syncthreads();
        #pragma unroll
        for (int i = 0; i < 2; i++) {
            int lin = t + i * 256;             // 64 rows x 8 slots of 8 bf16
            int r = lin >> 3, s = lin & 7;
            size_t gaddr = ((size_t)(b * Sk + k0 + r)) * D_MODEL + h * D_KH + s * 8;
            *(s16x8*)&Kl[r][s * 8] = *(const s16x8*)(K + gaddr);
            s16x8 vv = *(const s16x8*)(V + gaddr);
            #pragma unroll
            for (int j = 0; j < 8; j++) Vt[s * 8 + j][r] = ((unsigned short*)&vv)[j];
        }
        __syncthreads();

        f32x4 S[4];
        #pragma unroll
        for (int sub = 0; sub < 4; sub++) {
            BF8 b0, b1;
            b0.s = *(const s16x8*)&Kl[sub * 16 + c][8 * g];
            b1.s = *(const s16x8*)&Kl[sub * 16 + c][8 * g + 32];
            f32x4 s = (f32x4){0.f, 0.f, 0.f, 0.f};
            s = __builtin_amdgcn_mfma_f32_16x16x32_bf16(qf[0].b, b0.b, s, 0, 0, 0);
            s = __builtin_amdgcn_mfma_f32_16x16x32_bf16(qf[1].b, b1.b, s, 0, 0, 0);
            S[sub] = s;
        }

        int idv[4];
        #pragma unroll
        for (int sub = 0; sub < 4; sub++) idv[sub] = ids[b * Sk + k0 + sub * 16 + c];
        #pragma unroll
        for (int sub = 0; sub < 4; sub++) {
            int k = k0 + sub * 16 + c;
            bool pad = (idv[sub] == 0);
            #pragma unroll
            for (int r = 0; r < 4; r++) {
                int qrow = qbase + w * 16 + g * 4 + r;
                bool att = pad || (causal && k <= qrow);
                S[sub][r] = att ? S[sub][r] * 0.125f : -1e9f;
            }
        }

        #pragma unroll
        for (int r = 0; r < 4; r++) {
            float mx = fmaxf(fmaxf(S[0][r], S[1][r]), fmaxf(S[2][r], S[3][r]));
            #pragma unroll
            for (int o = 8; o > 0; o >>= 1) mx = fmaxf(mx, __shfl_xor(mx, o));
            float mn = fmaxf(m[r], mx);
            float sc = expf(m[r] - mn);
            float lsum = 0.f;
            #pragma unroll
            for (int sub = 0; sub < 4; sub++) {
                float p = expf(S[sub][r] - mn);
                S[sub][r] = p;
                lsum += p;
            }
            #pragma unroll
            for (int o = 8; o > 0; o >>= 1) lsum += __shfl_xor(lsum, o);
            l[r] = l[r] * sc + lsum;
            m[r] = mn;
            #pragma unroll
            for (int ds = 0; ds < 4; ds++) Oacc[ds][r] *= sc;
        }

        #pragma unroll
        for (int sub = 0; sub < 4; sub++)
            #pragma unroll
            for (int r = 0; r < 4; r++)
                Ps[w][g * 4 + r][sub * 16 + c] = f2b(S[sub][r]);

        #pragma unroll
        for (int kk = 0; kk < 2; kk++) {
            BF8 pa;
            pa.s = *(const s16x8*)&Ps[w][c][8 * g + kk * 32];
            #pragma unroll
            for (int ds = 0; ds < 4; ds++) {
                BF8 vb;
                vb.s = *(const s16x8*)&Vt[ds * 16 + c][8 * g + kk * 32];
                Oacc[ds] = __builtin_amdgcn_mfma_f32_16x16x32_bf16(pa.b, vb.b, Oacc[ds], 0, 0, 0);
            }
        }
    }

    #pragma unroll
    for (int r = 0; r < 4; r++) {
        float inv = 1.0f / l[r];
        int qrow = qbase + w * 16 + g * 4 + r;
        unsigned short* op = O_ + ((size_t)(b * Sq + qrow)) * D_MODEL + h * D_KH;
        #pragma unroll
        for (int ds = 0; ds < 4; ds++)
            op[ds * 16 + c] = f2b(Oacc[ds][r] * inv);
    }
}

// ---------------- layernorm(f + h), fp32 out + optional bf16 shadow -----------------
template<int WRITEB>
__global__ void ln_residual_kernel(const float* __restrict__ f, const float* __restrict__ h,
                                   const float* __restrict__ g, const float* __restrict__ bb,
                                   float* __restrict__ out, unsigned short* __restrict__ outb) {
    int row  = blockIdx.x * 4 + threadIdx.x / 64;
    int lane = threadIdx.x % 64;
    const float* fr = f + (size_t)row * D_MODEL;
    const float* hr = h + (size_t)row * D_MODEL;
    float v[8];
    float s = 0.f;
    #pragma unroll
    for (int i = 0; i < 8; i++) {
        v[i] = fr[lane + i * 64] + hr[lane + i * 64];
        s += v[i];
    }
    #pragma unroll
    for (int o = 32; o > 0; o >>= 1) s += __shfl_xor(s, o);
    float mu = s * (1.0f / 512.0f);
    float ss = 0.f;
    #pragma unroll
    for (int i = 0; i < 8; i++) { float d = v[i] - mu; ss += d * d; }
    #pragma unroll
    for (int o = 32; o > 0; o >>= 1) ss += __shfl_xor(ss, o);
    float var = ss * (1.0f / 512.0f);
    float inv = 1.0f / sqrtf(var + 1e-6f);
    #pragma unroll
    for (int i = 0; i < 8; i++) {
        int d = lane + i * 64;
        float o2 = g[d] * (v[i] - mu) * inv + bb[d];
        out[(size_t)row * D_MODEL + d] = o2;
        if (WRITEB) outb[(size_t)row * D_MODEL + d] = f2b(o2);
    }
}

extern "C" void kernel_launch(void* const* d_in, const int* in_sizes, int n_in,
                              void* d_out, int out_size, void* d_ws, size_t ws_size,
                              hipStream_t stream) {
    const int*   dec     = (const int*)d_in[0];
    const int*   enc_ids = (const int*)d_in[1];
    const float* enc_out = (const float*)d_in[2];
    const float* emb     = (const float*)d_in[3];
    const float* self_W  = (const float*)d_in[4];
    const float* self_b  = (const float*)d_in[5];
    const float* enc_W   = (const float*)d_in[6];
    const float* enc_b   = (const float*)d_in[7];
    const float* W1      = (const float*)d_in[8];
    const float* b1      = (const float*)d_in[9];
    const float* W2      = (const float*)d_in[10];
    const float* b2      = (const float*)d_in[11];
    const float* ln_g    = (const float*)d_in[12];
    const float* ln_b    = (const float*)d_in[13];
    float* out = (float*)d_out;

    const size_t NTOK = (size_t)BSZ * SEQ;      // 4096
    // ws: x(8MB f32) + bA(8MB f32) + xb(4MB bf16) + encb(4MB bf16) + 16MB bf16 region
    float* x  = (float*)d_ws;
    float* bA = x + NTOK * D_MODEL;
    unsigned short* xb   = (unsigned short*)(bA + NTOK * D_MODEL);
    unsigned short* encb = xb + NTOK * D_MODEL;
    unsigned short* bQ = encb + NTOK * D_MODEL;
    unsigned short* bK = bQ + NTOK * D_MODEL;
    unsigned short* bV = bK + NTOK * D_MODEL;
    unsigned short* bD = bV + NTOK * D_MODEL;
    unsigned short* bH = bQ;                    // 4096*2048 bf16 = 16MB, aliases bQ..bD

    dim3 blk(256);
    embed_kernel<<<dim3((unsigned)(NTOK * D_MODEL / 256)), blk, 0, stream>>>(dec, emb, x, xb);
    cvt_bf16_kernel<<<dim3((unsigned)(NTOK * D_MODEL / 4 / 256)), blk, 0, stream>>>(enc_out, encb, (int)(NTOK * D_MODEL / 4));

    int M = (int)NTOK;
    dim3 gp (M / 64, D_MODEL / 64);    // proj: 64 x 8
    dim3 gf1(M / 64, D_FF   / 64);     // FFN1: 64 x 32
    dim3 gf2(M / 64, D_MODEL / 64);    // FFN2: 64 x 8
    int nAttnBlk = BSZ * N_HEADS * (SEQ / 64);

    const size_t WSTRIDE = (size_t)D_MODEL * D_MODEL;
    for (int L = 0; L < N_LAYERS; L++) {
        const float* sW = self_W + (size_t)L * 4 * WSTRIDE;
        const float* sb = self_b + (size_t)L * 4 * D_MODEL;
        const float* eW = enc_W  + (size_t)L * 4 * WSTRIDE;
        const float* eb = enc_b  + (size_t)L * 4 * D_MODEL;
        const float* g  = ln_g   + (size_t)L * 3 * D_MODEL;
        const float* bs = ln_b   + (size_t)L * 3 * D_MODEL;

        // ---- self attention ----
        gemm_mfma_kernel<1,0><<<gp, blk, 0, stream>>>(xb, sW + 0 * WSTRIDE, sb + 0 * D_MODEL, bQ, M, D_MODEL, D_MODEL);
        gemm_mfma_kernel<1,0><<<gp, blk, 0, stream>>>(xb, sW + 1 * WSTRIDE, sb + 1 * D_MODEL, bK, M, D_MODEL, D_MODEL);
        gemm_mfma_kernel<1,0><<<gp, blk, 0, stream>>>(xb, sW + 2 * WSTRIDE, sb + 2 * D_MODEL, bV, M, D_MODEL, D_MODEL);
        attn_kernel<<<dim3(nAttnBlk), blk, 0, stream>>>(bQ, bK, bV, dec, bD, SEQ, SEQ, 1);
        gemm_mfma_kernel<0,0><<<gp, blk, 0, stream>>>(bD, sW + 3 * WSTRIDE, sb + 3 * D_MODEL, bA, M, D_MODEL, D_MODEL);
        ln_residual_kernel<1><<<dim3(M / 4), blk, 0, stream>>>(bA, x, g + 0 * D_MODEL, bs + 0 * D_MODEL, x, xb);

        // ---- cross attention (K/V from encoder outputs) ----
        gemm_mfma_kernel<1,0><<<gp, blk, 0, stream>>>(xb,   eW + 0 * WSTRIDE, eb + 0 * D_MODEL, bQ, M, D_MODEL, D_MODEL);
        gemm_mfma_kernel<1,0><<<gp, blk, 0, stream>>>(encb, eW + 1 * WSTRIDE, eb + 1 * D_MODEL, bK, M, D_MODEL, D_MODEL);
        gemm_mfma_kernel<1,0><<<gp, blk, 0, stream>>>(encb, eW + 2 * WSTRIDE, eb + 2 * D_MODEL, bV, M, D_MODEL, D_MODEL);
        attn_kernel<<<dim3(nAttnBlk), blk, 0, stream>>>(bQ, bK, bV, enc_ids, bD, SEQ, SEQ, 0);
        gemm_mfma_kernel<0,0><<<gp, blk, 0, stream>>>(bD, eW + 3 * WSTRIDE, eb + 3 * D_MODEL, bA, M, D_MODEL, D_MODEL);
        ln_residual_kernel<1><<<dim3(M / 4), blk, 0, stream>>>(bA, x, g + 1 * D_MODEL, bs + 1 * D_MODEL, x, xb);

        // ---- FFN ----
        gemm_mfma_kernel<1,1><<<gf1, blk, 0, stream>>>(xb, W1 + (size_t)L * D_MODEL * D_FF, b1 + (size_t)L * D_FF,    bH, M, D_FF,    D_MODEL);
        gemm_mfma_kernel<0,0><<<gf2, blk, 0, stream>>>(bH, W2 + (size_t)L * D_FF * D_MODEL, b2 + (size_t)L * D_MODEL, bA, M, D_MODEL, D_FF);
        float* lnout = (L == N_LAYERS - 1) ? out : x;
        ln_residual_kernel<1><<<dim3(M / 4), blk, 0, stream>>>(bA, x, g + 2 * D_MODEL, bs + 2 * D_MODEL, lnout, xb);
    }
}

// Round 5
// 901.714 us; speedup vs baseline: 9.1355x; 1.4476x over previous
//
#include <hip/hip_runtime.h>
#include <math.h>

#define D_MODEL 512
#define N_HEADS 8
#define D_KH    64
#define D_FF    2048
#define N_LAYERS 4
#define BSZ     4
#define SEQ     1024

typedef __attribute__((ext_vector_type(8))) __bf16 bf16x8;
typedef __attribute__((ext_vector_type(8))) short  s16x8;
typedef __attribute__((ext_vector_type(4))) float  f32x4;

union BF8 { s16x8 s; bf16x8 b; };

static __device__ inline unsigned short f2b(float f) {
    unsigned u = __float_as_uint(f);
    unsigned r = (u + 0x7fffu + ((u >> 16) & 1u)) >> 16;   // RNE
    return (unsigned short)r;
}

// ---------------- embedding + sinusoid positional encoding (fp32 + bf16 shadow) -----
__global__ void embed_kernel(const int* __restrict__ dec, const float* __restrict__ emb,
                             float* __restrict__ x, unsigned short* __restrict__ xb) {
    int idx = blockIdx.x * blockDim.x + threadIdx.x;  // over BSZ*SEQ*D_MODEL
    int d  = idx % D_MODEL;
    int bs = idx / D_MODEL;
    int s  = bs % SEQ;
    int tok = dec[bs];
    float pos = (float)(s + 5);                        // reference indexes positions 5..S+4
    float e = (float)(d & ~1) / (float)D_MODEL;
    float denom = powf(10000.0f, e);
    float ang = pos / denom;
    float pe = (d & 1) ? cosf(ang) : sinf(ang);
    float v = emb[(size_t)tok * D_MODEL + d] + pe;
    x[idx] = v;
    xb[idx] = f2b(v);
}

// ---------------- fp32 -> bf16 bulk convert (enc_out, once) -------------------------
__global__ void cvt_bf16_kernel(const float* __restrict__ in, unsigned short* __restrict__ outp, int n4) {
    int i = blockIdx.x * blockDim.x + threadIdx.x;
    if (i < n4) {
        float4 f = ((const float4*)in)[i];
        ushort4 h;
        h.x = f2b(f.x); h.y = f2b(f.y); h.z = f2b(f.z); h.w = f2b(f.w);
        ((ushort4*)outp)[i] = h;
    }
}

// ---------------- mask prep: enc pad-key compaction + dec pad-tile flags ------------
// one 64-lane wave per batch
__global__ void prep_kernel(const int* __restrict__ dec, const int* __restrict__ enc,
                            int* __restrict__ cntEnc, int* __restrict__ listEnc,
                            int* __restrict__ anyPadDec) {
    int b = blockIdx.x;
    int lane = threadIdx.x;
    int base = 0;
    for (int c0 = 0; c0 < SEQ; c0 += 64) {
        bool z = (enc[b * SEQ + c0 + lane] == 0);
        unsigned long long mask = __ballot(z);
        int pre = __popcll(mask & ((1ull << lane) - 1ull));
        if (z) listEnc[b * SEQ + base + pre] = c0 + lane;
        base += __popcll(mask);
    }
    if (lane == 0) cntEnc[b] = base;
    for (int c0 = 0; c0 < SEQ; c0 += 64) {
        bool z = (dec[b * SEQ + c0 + lane] == 0);
        unsigned long long mask = __ballot(z);
        if (lane == 0) anyPadDec[b * (SEQ / 64) + (c0 >> 6)] = (mask != 0ull) ? 1 : 0;
    }
}

// ---------------- bf16 MFMA GEMM, double-buffered, reg-prefetched -------------------
template<int OUTBF16, int RELU>
__launch_bounds__(256, 4)
__global__ void gemm_mfma_kernel(const unsigned short* __restrict__ A, const float* __restrict__ W,
                                 const float* __restrict__ bias, void* __restrict__ C_,
                                 int M, int N, int K) {
    __shared__ unsigned short As[2][64][72];
    __shared__ unsigned short Ws[2][64][72];
    int m0 = blockIdx.x * 64, n0 = blockIdx.y * 64;   // x fastest: neighbors share W panel
    int t = threadIdx.x;
    int w = t >> 6, lane = t & 63;
    int wm = w >> 1, wn = w & 1;
    int g = lane >> 4, c = lane & 15;

    int ar0 = t >> 3,            as0 = t & 7;
    int ar1 = (t + 256) >> 3,    as1 = (t + 256) & 7;
    int ukp[4], unp[4];
    #pragma unroll
    for (int p = 0; p < 4; p++) { int u = t + p * 256; ukp[p] = u >> 5; unp[p] = u & 31; }

    s16x8  aReg0, aReg1;
    float2 wReg[4][2];

    f32x4 acc[2][2];
    #pragma unroll
    for (int mi = 0; mi < 2; mi++)
        #pragma unroll
        for (int nj = 0; nj < 2; nj++) acc[mi][nj] = (f32x4){0.f, 0.f, 0.f, 0.f};

#define ISSUE_LOADS(KT) do {                                                         \
        int k0_ = (KT) * 64;                                                         \
        aReg0 = *(const s16x8*)(A + (size_t)(m0 + ar0) * K + k0_ + as0 * 8);         \
        aReg1 = *(const s16x8*)(A + (size_t)(m0 + ar1) * K + k0_ + as1 * 8);         \
        _Pragma("unroll")                                                            \
        for (int p = 0; p < 4; p++) {                                                \
            int k_ = k0_ + ukp[p] * 2, n_ = n0 + unp[p] * 2;                         \
            wReg[p][0] = *(const float2*)(W + (size_t)k_ * N + n_);                  \
            wReg[p][1] = *(const float2*)(W + (size_t)(k_ + 1) * N + n_);            \
        }                                                                            \
    } while (0)

#define STORE_LDS(B) do {                                                            \
        *(s16x8*)&As[B][ar0][as0 * 8] = aReg0;                                       \
        *(s16x8*)&As[B][ar1][as1 * 8] = aReg1;                                       \
        _Pragma("unroll")                                                            \
        for (int p = 0; p < 4; p++) {                                                \
            unsigned lo = (unsigned)f2b(wReg[p][0].x) | ((unsigned)f2b(wReg[p][1].x) << 16); \
            unsigned hi = (unsigned)f2b(wReg[p][0].y) | ((unsigned)f2b(wReg[p][1].y) << 16); \
            *(unsigned*)&Ws[B][unp[p] * 2    ][ukp[p] * 2] = lo;                     \
            *(unsigned*)&Ws[B][unp[p] * 2 + 1][ukp[p] * 2] = hi;                     \
        }                                                                            \
    } while (0)

    int nt = K >> 6;
    ISSUE_LOADS(0);
    STORE_LDS(0);
    for (int kt = 0; kt < nt; ++kt) {
        int cur = kt & 1;
        if (kt + 1 < nt) ISSUE_LOADS(kt + 1);
        __syncthreads();
        BF8 a[2][2], b[2][2];
        #pragma unroll
        for (int kk = 0; kk < 2; kk++) {
            #pragma unroll
            for (int mi = 0; mi < 2; mi++)
                a[kk][mi].s = *(const s16x8*)&As[cur][wm * 32 + mi * 16 + c][kk * 32 + 8 * g];
            #pragma unroll
            for (int nj = 0; nj < 2; nj++)
                b[kk][nj].s = *(const s16x8*)&Ws[cur][wn * 32 + nj * 16 + c][kk * 32 + 8 * g];
        }
        #pragma unroll
        for (int kk = 0; kk < 2; kk++)
            #pragma unroll
            for (int mi = 0; mi < 2; mi++)
                #pragma unroll
                for (int nj = 0; nj < 2; nj++)
                    acc[mi][nj] = __builtin_amdgcn_mfma_f32_16x16x32_bf16(a[kk][mi].b, b[kk][nj].b, acc[mi][nj], 0, 0, 0);
        if (kt + 1 < nt) STORE_LDS((kt + 1) & 1);
    }
#undef ISSUE_LOADS
#undef STORE_LDS

    #pragma unroll
    for (int mi = 0; mi < 2; mi++) {
        #pragma unroll
        for (int nj = 0; nj < 2; nj++) {
            #pragma unroll
            for (int r = 0; r < 4; r++) {
                int row = m0 + wm * 32 + mi * 16 + g * 4 + r;
                int col = n0 + wn * 32 + nj * 16 + c;
                float v = acc[mi][nj][r] + bias[col];
                if (RELU) v = fmaxf(v, 0.0f);
                if (OUTBF16) ((unsigned short*)C_)[(size_t)row * N + col] = f2b(v);
                else         ((float*)C_)[(size_t)row * N + col] = v;
            }
        }
    }
}

// ---------------- MFMA bf16 flash attention, mask-aware tile skipping ----------------
// MODE 1: causal self-attn — tiles kt<=qt always; kt>qt only if anyPad[b,kt]
//         (pad keys attend everywhere); att = (ids[k]==0) || k<=q.
// MODE 0: cross-attn over COMPACTED key list (att only where enc pad). If cnt==0,
//         full pass with att=false -> exact uniform softmax (= reference).
#define RS 72
template<int MODE>
__global__ void attn_kernel(const unsigned short* __restrict__ Q, const unsigned short* __restrict__ K,
                            const unsigned short* __restrict__ V, const int* __restrict__ ids,
                            const int* __restrict__ list, const int* __restrict__ cnt,
                            const int* __restrict__ anyPad,
                            unsigned short* __restrict__ O_, int Sq, int Sk) {
    __shared__ unsigned short Kl[64][RS];      // K rows: [k][d]
    __shared__ unsigned short Vt[64][RS];      // V transposed: [d][k]
    __shared__ unsigned short Ps[4][16][RS];   // per-wave P: [q][k]

    int blk = blockIdx.x;
    int qt = blk % (Sq / 64);
    int bh = blk / (Sq / 64);
    int h = bh % N_HEADS;
    int b = bh / N_HEADS;
    int qbase = qt * 64;
    int t = threadIdx.x;
    int w = t >> 6, lane = t & 63;
    int g = lane >> 4, c = lane & 15;

    BF8 qf[2];
    {
        int qrow = qbase + w * 16 + c;
        const unsigned short* qp = Q + ((size_t)(b * Sq + qrow)) * D_MODEL + h * D_KH;
        qf[0].s = *(const s16x8*)(qp + 8 * g);
        qf[1].s = *(const s16x8*)(qp + 8 * g + 32);
    }

    int nk = 0;             // cross: #gathered keys
    bool gathered = false;
    int totTiles;
    if (MODE) {
        totTiles = Sk >> 6;
    } else {
        nk = cnt[b];
        if (nk > 0) { gathered = true; totTiles = (nk + 63) >> 6; }
        else        { totTiles = Sk >> 6; }
    }

    float m[4], l[4];
    f32x4 Oacc[4];
    #pragma unroll
    for (int r = 0; r < 4; r++) { m[r] = -INFINITY; l[r] = 0.0f; }
    #pragma unroll
    for (int ds = 0; ds < 4; ds++) Oacc[ds] = (f32x4){0.f, 0.f, 0.f, 0.f};

    for (int kt = 0; kt < totTiles; kt++) {
        if (MODE && kt > qt && !anyPad[b * (Sk >> 6) + kt]) continue;   // block-uniform
        int k0 = kt * 64;
        __syncthreads();
        // ---- stage K rows (8 thr/row, coalesced 16B chunks; gather via list in cross) ----
        #pragma unroll
        for (int i = 0; i < 2; i++) {
            int lin = t + i * 256;
            int r = lin >> 3, s = lin & 7;
            int krow;
            if (gathered) { int li = k0 + r; krow = list[b * Sk + (li < nk ? li : nk - 1)]; }
            else krow = k0 + r;
            *(s16x8*)&Kl[r][s * 8] = *(const s16x8*)(K + ((size_t)(b * Sk + krow)) * D_MODEL + h * D_KH + s * 8);
        }
        // ---- stage V transposed: lane = k-row (writes span all 32 banks: conflict-free) ----
        {
            int li = k0 + lane;
            int vrow;
            if (gathered) vrow = list[b * Sk + (li < nk ? li : nk - 1)];
            else vrow = li;
            const unsigned short* vp = V + ((size_t)(b * Sk + vrow)) * D_MODEL + h * D_KH + w * 16;
            s16x8 v0 = *(const s16x8*)(vp);
            s16x8 v1 = *(const s16x8*)(vp + 8);
            #pragma unroll
            for (int j = 0; j < 8; j++) Vt[w * 16 + j][lane] = ((unsigned short*)&v0)[j];
            #pragma unroll
            for (int j = 0; j < 8; j++) Vt[w * 16 + 8 + j][lane] = ((unsigned short*)&v1)[j];
        }
        __syncthreads();

        f32x4 S[4];
        #pragma unroll
        for (int sub = 0; sub < 4; sub++) {
            BF8 b0, b1;
            b0.s = *(const s16x8*)&Kl[sub * 16 + c][8 * g];
            b1.s = *(const s16x8*)&Kl[sub * 16 + c][8 * g + 32];
            f32x4 s = (f32x4){0.f, 0.f, 0.f, 0.f};
            s = __builtin_amdgcn_mfma_f32_16x16x32_bf16(qf[0].b, b0.b, s, 0, 0, 0);
            s = __builtin_amdgcn_mfma_f32_16x16x32_bf16(qf[1].b, b1.b, s, 0, 0, 0);
            S[sub] = s;
        }

        // ---- mask + scale ----
        #pragma unroll
        for (int sub = 0; sub < 4; sub++) {
            int k = k0 + sub * 16 + c;
            bool pad;
            if (MODE) pad = (ids[b * Sk + k] == 0);
            else      pad = gathered ? (k < nk) : false;
            #pragma unroll
            for (int r = 0; r < 4; r++) {
                bool att;
                if (MODE) {
                    int qrow = qbase + w * 16 + g * 4 + r;
                    att = pad || (k <= qrow);
                } else att = pad;
                S[sub][r] = att ? S[sub][r] * 0.125f : -1e9f;
            }
        }

        // ---- online softmax per row ----
        #pragma unroll
        for (int r = 0; r < 4; r++) {
            float mx = fmaxf(fmaxf(S[0][r], S[1][r]), fmaxf(S[2][r], S[3][r]));
            #pragma unroll
            for (int o = 8; o > 0; o >>= 1) mx = fmaxf(mx, __shfl_xor(mx, o));
            float mn = fmaxf(m[r], mx);
            float sc = __expf(m[r] - mn);
            float lsum = 0.f;
            #pragma unroll
            for (int sub = 0; sub < 4; sub++) {
                float p = __expf(S[sub][r] - mn);
                S[sub][r] = p;
                lsum += p;
            }
            #pragma unroll
            for (int o = 8; o > 0; o >>= 1) lsum += __shfl_xor(lsum, o);
            l[r] = l[r] * sc + lsum;
            m[r] = mn;
            #pragma unroll
            for (int ds = 0; ds < 4; ds++) Oacc[ds][r] *= sc;
        }

        #pragma unroll
        for (int sub = 0; sub < 4; sub++)
            #pragma unroll
            for (int r = 0; r < 4; r++)
                Ps[w][g * 4 + r][sub * 16 + c] = f2b(S[sub][r]);

        #pragma unroll
        for (int kk = 0; kk < 2; kk++) {
            BF8 pa;
            pa.s = *(const s16x8*)&Ps[w][c][8 * g + kk * 32];
            #pragma unroll
            for (int ds = 0; ds < 4; ds++) {
                BF8 vb;
                vb.s = *(const s16x8*)&Vt[ds * 16 + c][8 * g + kk * 32];
                Oacc[ds] = __builtin_amdgcn_mfma_f32_16x16x32_bf16(pa.b, vb.b, Oacc[ds], 0, 0, 0);
            }
        }
    }

    #pragma unroll
    for (int r = 0; r < 4; r++) {
        float inv = 1.0f / l[r];
        int qrow = qbase + w * 16 + g * 4 + r;
        unsigned short* op = O_ + ((size_t)(b * Sq + qrow)) * D_MODEL + h * D_KH;
        #pragma unroll
        for (int ds = 0; ds < 4; ds++)
            op[ds * 16 + c] = f2b(Oacc[ds][r] * inv);
    }
}

// ---------------- layernorm(f + h), fp32 out + optional bf16 shadow -----------------
template<int WRITEB>
__global__ void ln_residual_kernel(const float* __restrict__ f, const float* __restrict__ h,
                                   const float* __restrict__ g, const float* __restrict__ bb,
                                   float* __restrict__ out, unsigned short* __restrict__ outb) {
    int row  = blockIdx.x * 4 + threadIdx.x / 64;
    int lane = threadIdx.x % 64;
    const float* fr = f + (size_t)row * D_MODEL;
    const float* hr = h + (size_t)row * D_MODEL;
    float v[8];
    float s = 0.f;
    #pragma unroll
    for (int i = 0; i < 8; i++) {
        v[i] = fr[lane + i * 64] + hr[lane + i * 64];
        s += v[i];
    }
    #pragma unroll
    for (int o = 32; o > 0; o >>= 1) s += __shfl_xor(s, o);
    float mu = s * (1.0f / 512.0f);
    float ss = 0.f;
    #pragma unroll
    for (int i = 0; i < 8; i++) { float d = v[i] - mu; ss += d * d; }
    #pragma unroll
    for (int o = 32; o > 0; o >>= 1) ss += __shfl_xor(ss, o);
    float var = ss * (1.0f / 512.0f);
    float inv = 1.0f / sqrtf(var + 1e-6f);
    #pragma unroll
    for (int i = 0; i < 8; i++) {
        int d = lane + i * 64;
        float o2 = g[d] * (v[i] - mu) * inv + bb[d];
        out[(size_t)row * D_MODEL + d] = o2;
        if (WRITEB) outb[(size_t)row * D_MODEL + d] = f2b(o2);
    }
}

extern "C" void kernel_launch(void* const* d_in, const int* in_sizes, int n_in,
                              void* d_out, int out_size, void* d_ws, size_t ws_size,
                              hipStream_t stream) {
    const int*   dec     = (const int*)d_in[0];
    const int*   enc_ids = (const int*)d_in[1];
    const float* enc_out = (const float*)d_in[2];
    const float* emb     = (const float*)d_in[3];
    const float* self_W  = (const float*)d_in[4];
    const float* self_b  = (const float*)d_in[5];
    const float* enc_W   = (const float*)d_in[6];
    const float* enc_b   = (const float*)d_in[7];
    const float* W1      = (const float*)d_in[8];
    const float* b1      = (const float*)d_in[9];
    const float* W2      = (const float*)d_in[10];
    const float* b2      = (const float*)d_in[11];
    const float* ln_g    = (const float*)d_in[12];
    const float* ln_b    = (const float*)d_in[13];
    float* out = (float*)d_out;

    const size_t NTOK = (size_t)BSZ * SEQ;      // 4096
    float* x  = (float*)d_ws;
    float* bA = x + NTOK * D_MODEL;
    unsigned short* xb   = (unsigned short*)(bA + NTOK * D_MODEL);
    unsigned short* encb = xb + NTOK * D_MODEL;
    unsigned short* bQ = encb + NTOK * D_MODEL;
    unsigned short* bK = bQ + NTOK * D_MODEL;
    unsigned short* bV = bK + NTOK * D_MODEL;
    unsigned short* bD = bV + NTOK * D_MODEL;
    unsigned short* bH = bQ;                    // 4096*2048 bf16 = 16MB, aliases bQ..bD
    int* cntEnc    = (int*)(bD + NTOK * D_MODEL);
    int* anyPadDec = cntEnc + BSZ;
    int* listEnc   = anyPadDec + BSZ * (SEQ / 64);

    dim3 blk(256);
    embed_kernel<<<dim3((unsigned)(NTOK * D_MODEL / 256)), blk, 0, stream>>>(dec, emb, x, xb);
    cvt_bf16_kernel<<<dim3((unsigned)(NTOK * D_MODEL / 4 / 256)), blk, 0, stream>>>(enc_out, encb, (int)(NTOK * D_MODEL / 4));
    prep_kernel<<<dim3(BSZ), dim3(64), 0, stream>>>(dec, enc_ids, cntEnc, listEnc, anyPadDec);

    int M = (int)NTOK;
    dim3 gp (M / 64, D_MODEL / 64);    // proj: 64 x 8
    dim3 gf1(M / 64, D_FF   / 64);     // FFN1: 64 x 32
    dim3 gf2(M / 64, D_MODEL / 64);    // FFN2: 64 x 8
    int nAttnBlk = BSZ * N_HEADS * (SEQ / 64);

    const size_t WSTRIDE = (size_t)D_MODEL * D_MODEL;
    for (int L = 0; L < N_LAYERS; L++) {
        const float* sW = self_W + (size_t)L * 4 * WSTRIDE;
        const float* sb = self_b + (size_t)L * 4 * D_MODEL;
        const float* eW = enc_W  + (size_t)L * 4 * WSTRIDE;
        const float* eb = enc_b  + (size_t)L * 4 * D_MODEL;
        const float* g  = ln_g   + (size_t)L * 3 * D_MODEL;
        const float* bs = ln_b   + (size_t)L * 3 * D_MODEL;

        // ---- self attention ----
        gemm_mfma_kernel<1,0><<<gp, blk, 0, stream>>>(xb, sW + 0 * WSTRIDE, sb + 0 * D_MODEL, bQ, M, D_MODEL, D_MODEL);
        gemm_mfma_kernel<1,0><<<gp, blk, 0, stream>>>(xb, sW + 1 * WSTRIDE, sb + 1 * D_MODEL, bK, M, D_MODEL, D_MODEL);
        gemm_mfma_kernel<1,0><<<gp, blk, 0, stream>>>(xb, sW + 2 * WSTRIDE, sb + 2 * D_MODEL, bV, M, D_MODEL, D_MODEL);
        attn_kernel<1><<<dim3(nAttnBlk), blk, 0, stream>>>(bQ, bK, bV, dec, listEnc, cntEnc, anyPadDec, bD, SEQ, SEQ);
        gemm_mfma_kernel<0,0><<<gp, blk, 0, stream>>>(bD, sW + 3 * WSTRIDE, sb + 3 * D_MODEL, bA, M, D_MODEL, D_MODEL);
        ln_residual_kernel<1><<<dim3(M / 4), blk, 0, stream>>>(bA, x, g + 0 * D_MODEL, bs + 0 * D_MODEL, x, xb);

        // ---- cross attention (K/V from encoder outputs, compacted pad-key list) ----
        gemm_mfma_kernel<1,0><<<gp, blk, 0, stream>>>(xb,   eW + 0 * WSTRIDE, eb + 0 * D_MODEL, bQ, M, D_MODEL, D_MODEL);
        gemm_mfma_kernel<1,0><<<gp, blk, 0, stream>>>(encb, eW + 1 * WSTRIDE, eb + 1 * D_MODEL, bK, M, D_MODEL, D_MODEL);
        gemm_mfma_kernel<1,0><<<gp, blk, 0, stream>>>(encb, eW + 2 * WSTRIDE, eb + 2 * D_MODEL, bV, M, D_MODEL, D_MODEL);
        attn_kernel<0><<<dim3(nAttnBlk), blk, 0, stream>>>(bQ, bK, bV, enc_ids, listEnc, cntEnc, anyPadDec, bD, SEQ, SEQ);
        gemm_mfma_kernel<0,0><<<gp, blk, 0, stream>>>(bD, eW + 3 * WSTRIDE, eb + 3 * D_MODEL, bA, M, D_MODEL, D_MODEL);
        ln_residual_kernel<1><<<dim3(M / 4), blk, 0, stream>>>(bA, x, g + 1 * D_MODEL, bs + 1 * D_MODEL, x, xb);

        // ---- FFN ----
        gemm_mfma_kernel<1,1><<<gf1, blk, 0, stream>>>(xb, W1 + (size_t)L * D_MODEL * D_FF, b1 + (size_t)L * D_FF,    bH, M, D_FF,    D_MODEL);
        gemm_mfma_kernel<0,0><<<gf2, blk, 0, stream>>>(bH, W2 + (size_t)L * D_FF * D_MODEL, b2 + (size_t)L * D_MODEL, bA, M, D_MODEL, D_FF);
        float* lnout = (L == N_LAYERS - 1) ? out : x;
        ln_residual_kernel<1><<<dim3(M / 4), blk, 0, stream>>>(bA, x, g + 2 * D_MODEL, bs + 2 * D_MODEL, lnout, xb);
    }
}

// Round 6
// 790.976 us; speedup vs baseline: 10.4145x; 1.1400x over previous
//
#include <hip/hip_runtime.h>
#include <math.h>

#define D_MODEL 512
#define N_HEADS 8
#define D_KH    64
#define D_FF    2048
#define N_LAYERS 4
#define BSZ     4
#define SEQ     1024

typedef __attribute__((ext_vector_type(8))) __bf16 bf16x8;
typedef __attribute__((ext_vector_type(8))) short  s16x8;
typedef __attribute__((ext_vector_type(4))) float  f32x4;

union BF8 { s16x8 s; bf16x8 b; };

static __device__ inline unsigned short f2b(float f) {
    unsigned u = __float_as_uint(f);
    unsigned r = (u + 0x7fffu + ((u >> 16) & 1u)) >> 16;   // RNE
    return (unsigned short)r;
}

// ---------------- embedding + sinusoid positional encoding (fp32 + bf16 shadow) -----
__global__ void embed_kernel(const int* __restrict__ dec, const float* __restrict__ emb,
                             float* __restrict__ x, unsigned short* __restrict__ xb) {
    int idx = blockIdx.x * blockDim.x + threadIdx.x;  // over BSZ*SEQ*D_MODEL
    int d  = idx % D_MODEL;
    int bs = idx / D_MODEL;
    int s  = bs % SEQ;
    int tok = dec[bs];
    float pos = (float)(s + 5);                        // reference indexes positions 5..S+4
    float e = (float)(d & ~1) / (float)D_MODEL;
    float denom = powf(10000.0f, e);
    float ang = pos / denom;
    float pe = (d & 1) ? cosf(ang) : sinf(ang);
    float v = emb[(size_t)tok * D_MODEL + d] + pe;
    x[idx] = v;
    xb[idx] = f2b(v);
}

// ---------------- fp32 -> bf16 bulk convert (enc_out, once) -------------------------
__global__ void cvt_bf16_kernel(const float* __restrict__ in, unsigned short* __restrict__ outp, int n4) {
    int i = blockIdx.x * blockDim.x + threadIdx.x;
    if (i < n4) {
        float4 f = ((const float4*)in)[i];
        ushort4 h;
        h.x = f2b(f.x); h.y = f2b(f.y); h.z = f2b(f.z); h.w = f2b(f.w);
        ((ushort4*)outp)[i] = h;
    }
}

// ---------------- mask prep: enc pad-key compaction + dec pad-tile flags ------------
__global__ void prep_kernel(const int* __restrict__ dec, const int* __restrict__ enc,
                            int* __restrict__ cntEnc, int* __restrict__ listEnc,
                            int* __restrict__ anyPadDec) {
    int b = blockIdx.x;
    int lane = threadIdx.x;
    int base = 0;
    for (int c0 = 0; c0 < SEQ; c0 += 64) {
        bool z = (enc[b * SEQ + c0 + lane] == 0);
        unsigned long long mask = __ballot(z);
        int pre = __popcll(mask & ((1ull << lane) - 1ull));
        if (z) listEnc[b * SEQ + base + pre] = c0 + lane;
        base += __popcll(mask);
    }
    if (lane == 0) cntEnc[b] = base;
    for (int c0 = 0; c0 < SEQ; c0 += 64) {
        bool z = (dec[b * SEQ + c0 + lane] == 0);
        unsigned long long mask = __ballot(z);
        if (lane == 0) anyPadDec[b * (SEQ / 64) + (c0 >> 6)] = (mask != 0ull) ? 1 : 0;
    }
}

// ---------------- bf16 MFMA GEMM, double-buffered, reg-prefetched -------------------
// QKV=1: blockIdx.y spans 3 concatenated 512-col weight matrices (contiguous in W);
//        j = y>>3 selects matrix, A1 used for j>=1, C1/C2 for j=1/2. N=K=512.
template<int OUTBF16, int RELU, int QKV>
__launch_bounds__(256, 4)
__global__ void gemm_mfma_kernel(const unsigned short* __restrict__ A, const unsigned short* __restrict__ A1,
                                 const float* __restrict__ W, const float* __restrict__ bias,
                                 void* __restrict__ C_, void* __restrict__ C1, void* __restrict__ C2,
                                 int M, int N, int K) {
    __shared__ unsigned short As[2][64][72];
    __shared__ unsigned short Ws[2][64][72];
    int m0 = blockIdx.x * 64, n0;
    if (QKV) {
        int j = blockIdx.y >> 3;
        n0 = (int)(blockIdx.y & 7) * 64;
        W += (size_t)j * (D_MODEL * D_MODEL);
        bias += j * D_MODEL;
        if (j) A = A1;
        if (j == 1) C_ = C1; else if (j == 2) C_ = C2;
    } else {
        n0 = blockIdx.y * 64;
    }
    int t = threadIdx.x;
    int w = t >> 6, lane = t & 63;
    int wm = w >> 1, wn = w & 1;
    int g = lane >> 4, c = lane & 15;

    int ar0 = t >> 3,            as0 = t & 7;
    int ar1 = (t + 256) >> 3,    as1 = (t + 256) & 7;
    int ukp[4], unp[4];
    #pragma unroll
    for (int p = 0; p < 4; p++) { int u = t + p * 256; ukp[p] = u >> 5; unp[p] = u & 31; }

    s16x8  aReg0, aReg1;
    float2 wReg[4][2];

    f32x4 acc[2][2];
    #pragma unroll
    for (int mi = 0; mi < 2; mi++)
        #pragma unroll
        for (int nj = 0; nj < 2; nj++) acc[mi][nj] = (f32x4){0.f, 0.f, 0.f, 0.f};

#define ISSUE_LOADS(KT) do {                                                         \
        int k0_ = (KT) * 64;                                                         \
        aReg0 = *(const s16x8*)(A + (size_t)(m0 + ar0) * K + k0_ + as0 * 8);         \
        aReg1 = *(const s16x8*)(A + (size_t)(m0 + ar1) * K + k0_ + as1 * 8);         \
        _Pragma("unroll")                                                            \
        for (int p = 0; p < 4; p++) {                                                \
            int k_ = k0_ + ukp[p] * 2, n_ = n0 + unp[p] * 2;                         \
            wReg[p][0] = *(const float2*)(W + (size_t)k_ * N + n_);                  \
            wReg[p][1] = *(const float2*)(W + (size_t)(k_ + 1) * N + n_);            \
        }                                                                            \
    } while (0)

#define STORE_LDS(B) do {                                                            \
        *(s16x8*)&As[B][ar0][as0 * 8] = aReg0;                                       \
        *(s16x8*)&As[B][ar1][as1 * 8] = aReg1;                                       \
        _Pragma("unroll")                                                            \
        for (int p = 0; p < 4; p++) {                                                \
            unsigned lo = (unsigned)f2b(wReg[p][0].x) | ((unsigned)f2b(wReg[p][1].x) << 16); \
            unsigned hi = (unsigned)f2b(wReg[p][0].y) | ((unsigned)f2b(wReg[p][1].y) << 16); \
            *(unsigned*)&Ws[B][unp[p] * 2    ][ukp[p] * 2] = lo;                     \
            *(unsigned*)&Ws[B][unp[p] * 2 + 1][ukp[p] * 2] = hi;                     \
        }                                                                            \
    } while (0)

    int nt = K >> 6;
    ISSUE_LOADS(0);
    STORE_LDS(0);
    for (int kt = 0; kt < nt; ++kt) {
        int cur = kt & 1;
        if (kt + 1 < nt) ISSUE_LOADS(kt + 1);
        __syncthreads();
        BF8 a[2][2], b[2][2];
        #pragma unroll
        for (int kk = 0; kk < 2; kk++) {
            #pragma unroll
            for (int mi = 0; mi < 2; mi++)
                a[kk][mi].s = *(const s16x8*)&As[cur][wm * 32 + mi * 16 + c][kk * 32 + 8 * g];
            #pragma unroll
            for (int nj = 0; nj < 2; nj++)
                b[kk][nj].s = *(const s16x8*)&Ws[cur][wn * 32 + nj * 16 + c][kk * 32 + 8 * g];
        }
        #pragma unroll
        for (int kk = 0; kk < 2; kk++)
            #pragma unroll
            for (int mi = 0; mi < 2; mi++)
                #pragma unroll
                for (int nj = 0; nj < 2; nj++)
                    acc[mi][nj] = __builtin_amdgcn_mfma_f32_16x16x32_bf16(a[kk][mi].b, b[kk][nj].b, acc[mi][nj], 0, 0, 0);
        if (kt + 1 < nt) STORE_LDS((kt + 1) & 1);
    }
#undef ISSUE_LOADS
#undef STORE_LDS

    #pragma unroll
    for (int mi = 0; mi < 2; mi++) {
        #pragma unroll
        for (int nj = 0; nj < 2; nj++) {
            #pragma unroll
            for (int r = 0; r < 4; r++) {
                int row = m0 + wm * 32 + mi * 16 + g * 4 + r;
                int col = n0 + wn * 32 + nj * 16 + c;
                float v = acc[mi][nj][r] + bias[col];
                if (RELU) v = fmaxf(v, 0.0f);
                if (OUTBF16) ((unsigned short*)C_)[(size_t)row * N + col] = f2b(v);
                else         ((float*)C_)[(size_t)row * N + col] = v;
            }
        }
    }
}

// ---------------- MFMA bf16 flash attention, balanced + reg-prefetched --------------
// MODE 1: causal self-attn, qt remapped so paired blocks (blk, blk+256) have
//         complementary work (qt, 15-qt) -> per-CU makespan constant (17 tiles).
// MODE 0: cross-attn over compacted enc-pad key list (uniform tiny work).
// Pipeline: regs hold tile i; barrier; regs->LDS; barrier; issue loads i+1; compute i.
#define RS 72
template<int MODE>
__global__ void attn_kernel(const unsigned short* __restrict__ Q, const unsigned short* __restrict__ K,
                            const unsigned short* __restrict__ V, const int* __restrict__ ids,
                            const int* __restrict__ list, const int* __restrict__ cnt,
                            const int* __restrict__ anyPad,
                            unsigned short* __restrict__ O_, int Sq, int Sk) {
    __shared__ unsigned short Kl[64][RS];      // K rows: [k][d]
    __shared__ unsigned short Vt[64][RS];      // V transposed: [d][k]
    __shared__ unsigned short Ps[4][16][RS];   // per-wave P: [q][k]
    __shared__ short act[16];
    __shared__ int nActS;

    int blk = blockIdx.x;
    int qt, bh;
    if (MODE) {
        int hi = blk >> 8, pair = blk & 255;
        bh = pair >> 3;
        int qtp = pair & 7;
        qt = hi ? (15 - qtp) : qtp;            // pair work: (qtp+1)+(16-qtp)=17 tiles
    } else {
        qt = blk & 15;
        bh = blk >> 4;
    }
    int h = bh % N_HEADS;
    int b = bh / N_HEADS;
    int qbase = qt * 64;
    int t = threadIdx.x;
    int w = t >> 6, lane = t & 63;
    int g = lane >> 4, c = lane & 15;

    BF8 qf[2];
    {
        int qrow = qbase + w * 16 + c;
        const unsigned short* qp = Q + ((size_t)(b * Sq + qrow)) * D_MODEL + h * D_KH;
        qf[0].s = *(const s16x8*)(qp + 8 * g);
        qf[1].s = *(const s16x8*)(qp + 8 * g + 32);
    }

    int nk = 0;
    bool gathered = false;
    if (!MODE) {
        nk = cnt[b];
        gathered = (nk > 0);
    }

    // active tile list
    if (t == 0) {
        int n = 0;
        if (MODE) {
            for (int kt2 = 0; kt2 < (Sk >> 6); kt2++)
                if (kt2 <= qt || anyPad[b * (Sk >> 6) + kt2]) act[n++] = (short)kt2;
        } else {
            int tt = gathered ? ((nk + 63) >> 6) : (Sk >> 6);
            for (int kt2 = 0; kt2 < tt; kt2++) act[n++] = (short)kt2;
        }
        nActS = n;
    }
    __syncthreads();
    int nAct = nActS;

    float m[4], l[4];
    f32x4 Oacc[4];
    #pragma unroll
    for (int r = 0; r < 4; r++) { m[r] = -INFINITY; l[r] = 0.0f; }
    #pragma unroll
    for (int ds = 0; ds < 4; ds++) Oacc[ds] = (f32x4){0.f, 0.f, 0.f, 0.f};

    s16x8 kreg0, kreg1, vreg0, vreg1;
    int kr0 = t >> 3,        ks0 = t & 7;
    int kr1 = (t + 256) >> 3, ks1 = (t + 256) & 7;

#define LOADT(KT) do {                                                                \
        int k0_ = (KT) * 64;                                                          \
        int krow0 = k0_ + kr0, krow1 = k0_ + kr1;                                     \
        if (gathered) {                                                               \
            krow0 = list[b * Sk + (krow0 < nk ? krow0 : nk - 1)];                     \
            krow1 = list[b * Sk + (krow1 < nk ? krow1 : nk - 1)];                     \
        }                                                                             \
        kreg0 = *(const s16x8*)(K + ((size_t)(b * Sk + krow0)) * D_MODEL + h * D_KH + ks0 * 8); \
        kreg1 = *(const s16x8*)(K + ((size_t)(b * Sk + krow1)) * D_MODEL + h * D_KH + ks1 * 8); \
        int li = k0_ + lane, vrow = li;                                               \
        if (gathered) vrow = list[b * Sk + (li < nk ? li : nk - 1)];                  \
        const unsigned short* vp = V + ((size_t)(b * Sk + vrow)) * D_MODEL + h * D_KH + w * 16; \
        vreg0 = *(const s16x8*)(vp);                                                  \
        vreg1 = *(const s16x8*)(vp + 8);                                              \
    } while (0)

    LOADT(act[0]);
    for (int i = 0; i < nAct; i++) {
        int k0 = (int)act[i] * 64;
        __syncthreads();                        // prev compute done reading LDS
        // ---- regs -> LDS ----
        *(s16x8*)&Kl[kr0][ks0 * 8] = kreg0;
        *(s16x8*)&Kl[kr1][ks1 * 8] = kreg1;
        #pragma unroll
        for (int j = 0; j < 8; j++) Vt[w * 16 + j][lane] = ((unsigned short*)&vreg0)[j];
        #pragma unroll
        for (int j = 0; j < 8; j++) Vt[w * 16 + 8 + j][lane] = ((unsigned short*)&vreg1)[j];
        __syncthreads();
        if (i + 1 < nAct) LOADT(act[i + 1]);    // latency hides under compute below

        // ---- S = Q K^T ----
        f32x4 S[4];
        #pragma unroll
        for (int sub = 0; sub < 4; sub++) {
            BF8 b0, b1;
            b0.s = *(const s16x8*)&Kl[sub * 16 + c][8 * g];
            b1.s = *(const s16x8*)&Kl[sub * 16 + c][8 * g + 32];
            f32x4 s = (f32x4){0.f, 0.f, 0.f, 0.f};
            s = __builtin_amdgcn_mfma_f32_16x16x32_bf16(qf[0].b, b0.b, s, 0, 0, 0);
            s = __builtin_amdgcn_mfma_f32_16x16x32_bf16(qf[1].b, b1.b, s, 0, 0, 0);
            S[sub] = s;
        }

        // ---- mask + scale ----
        #pragma unroll
        for (int sub = 0; sub < 4; sub++) {
            int k = k0 + sub * 16 + c;
            bool pad;
            if (MODE) pad = (ids[b * Sk + k] == 0);
            else      pad = gathered ? (k < nk) : false;
            #pragma unroll
            for (int r = 0; r < 4; r++) {
                bool att;
                if (MODE) {
                    int qrow = qbase + w * 16 + g * 4 + r;
                    att = pad || (k <= qrow);
                } else att = pad;
                S[sub][r] = att ? S[sub][r] * 0.125f : -1e9f;
            }
        }

        // ---- online softmax per row ----
        #pragma unroll
        for (int r = 0; r < 4; r++) {
            float mx = fmaxf(fmaxf(S[0][r], S[1][r]), fmaxf(S[2][r], S[3][r]));
            #pragma unroll
            for (int o = 8; o > 0; o >>= 1) mx = fmaxf(mx, __shfl_xor(mx, o));
            float mn = fmaxf(m[r], mx);
            float sc = __expf(m[r] - mn);
            float lsum = 0.f;
            #pragma unroll
            for (int sub = 0; sub < 4; sub++) {
                float p = __expf(S[sub][r] - mn);
                S[sub][r] = p;
                lsum += p;
            }
            #pragma unroll
            for (int o = 8; o > 0; o >>= 1) lsum += __shfl_xor(lsum, o);
            l[r] = l[r] * sc + lsum;
            m[r] = mn;
            #pragma unroll
            for (int ds = 0; ds < 4; ds++) Oacc[ds][r] *= sc;
        }

        #pragma unroll
        for (int sub = 0; sub < 4; sub++)
            #pragma unroll
            for (int r = 0; r < 4; r++)
                Ps[w][g * 4 + r][sub * 16 + c] = f2b(S[sub][r]);

        #pragma unroll
        for (int kk = 0; kk < 2; kk++) {
            BF8 pa;
            pa.s = *(const s16x8*)&Ps[w][c][8 * g + kk * 32];
            #pragma unroll
            for (int ds = 0; ds < 4; ds++) {
                BF8 vb;
                vb.s = *(const s16x8*)&Vt[ds * 16 + c][8 * g + kk * 32];
                Oacc[ds] = __builtin_amdgcn_mfma_f32_16x16x32_bf16(pa.b, vb.b, Oacc[ds], 0, 0, 0);
            }
        }
    }
#undef LOADT

    #pragma unroll
    for (int r = 0; r < 4; r++) {
        float inv = 1.0f / l[r];
        int qrow = qbase + w * 16 + g * 4 + r;
        unsigned short* op = O_ + ((size_t)(b * Sq + qrow)) * D_MODEL + h * D_KH;
        #pragma unroll
        for (int ds = 0; ds < 4; ds++)
            op[ds * 16 + c] = f2b(Oacc[ds][r] * inv);
    }
}

// ---------------- layernorm(f + h), fp32 out + optional bf16 shadow -----------------
template<int WRITEB>
__global__ void ln_residual_kernel(const float* __restrict__ f, const float* __restrict__ h,
                                   const float* __restrict__ g, const float* __restrict__ bb,
                                   float* __restrict__ out, unsigned short* __restrict__ outb) {
    int row  = blockIdx.x * 4 + threadIdx.x / 64;
    int lane = threadIdx.x % 64;
    const float* fr = f + (size_t)row * D_MODEL;
    const float* hr = h + (size_t)row * D_MODEL;
    float v[8];
    float s = 0.f;
    #pragma unroll
    for (int i = 0; i < 8; i++) {
        v[i] = fr[lane + i * 64] + hr[lane + i * 64];
        s += v[i];
    }
    #pragma unroll
    for (int o = 32; o > 0; o >>= 1) s += __shfl_xor(s, o);
    float mu = s * (1.0f / 512.0f);
    float ss = 0.f;
    #pragma unroll
    for (int i = 0; i < 8; i++) { float d = v[i] - mu; ss += d * d; }
    #pragma unroll
    for (int o = 32; o > 0; o >>= 1) ss += __shfl_xor(ss, o);
    float var = ss * (1.0f / 512.0f);
    float inv = 1.0f / sqrtf(var + 1e-6f);
    #pragma unroll
    for (int i = 0; i < 8; i++) {
        int d = lane + i * 64;
        float o2 = g[d] * (v[i] - mu) * inv + bb[d];
        out[(size_t)row * D_MODEL + d] = o2;
        if (WRITEB) outb[(size_t)row * D_MODEL + d] = f2b(o2);
    }
}

extern "C" void kernel_launch(void* const* d_in, const int* in_sizes, int n_in,
                              void* d_out, int out_size, void* d_ws, size_t ws_size,
                              hipStream_t stream) {
    const int*   dec     = (const int*)d_in[0];
    const int*   enc_ids = (const int*)d_in[1];
    const float* enc_out = (const float*)d_in[2];
    const float* emb     = (const float*)d_in[3];
    const float* self_W  = (const float*)d_in[4];
    const float* self_b  = (const float*)d_in[5];
    const float* enc_W   = (const float*)d_in[6];
    const float* enc_b   = (const float*)d_in[7];
    const float* W1      = (const float*)d_in[8];
    const float* b1      = (const float*)d_in[9];
    const float* W2      = (const float*)d_in[10];
    const float* b2      = (const float*)d_in[11];
    const float* ln_g    = (const float*)d_in[12];
    const float* ln_b    = (const float*)d_in[13];
    float* out = (float*)d_out;

    const size_t NTOK = (size_t)BSZ * SEQ;      // 4096
    float* x  = (float*)d_ws;
    float* bA = x + NTOK * D_MODEL;
    unsigned short* xb   = (unsigned short*)(bA + NTOK * D_MODEL);
    unsigned short* encb = xb + NTOK * D_MODEL;
    unsigned short* bQ = encb + NTOK * D_MODEL;
    unsigned short* bK = bQ + NTOK * D_MODEL;
    unsigned short* bV = bK + NTOK * D_MODEL;
    unsigned short* bD = bV + NTOK * D_MODEL;
    unsigned short* bH = bQ;                    // 4096*2048 bf16 = 16MB, aliases bQ..bD
    int* cntEnc    = (int*)(bD + NTOK * D_MODEL);
    int* anyPadDec = cntEnc + BSZ;
    int* listEnc   = anyPadDec + BSZ * (SEQ / 64);

    dim3 blk(256);
    embed_kernel<<<dim3((unsigned)(NTOK * D_MODEL / 256)), blk, 0, stream>>>(dec, emb, x, xb);
    cvt_bf16_kernel<<<dim3((unsigned)(NTOK * D_MODEL / 4 / 256)), blk, 0, stream>>>(enc_out, encb, (int)(NTOK * D_MODEL / 4));
    prep_kernel<<<dim3(BSZ), dim3(64), 0, stream>>>(dec, enc_ids, cntEnc, listEnc, anyPadDec);

    int M = (int)NTOK;
    dim3 gqkv(M / 64, 24);             // merged QKV: 1536 blocks
    dim3 gp  (M / 64, D_MODEL / 64);   // single proj: 512 blocks
    dim3 gf1 (M / 64, D_FF   / 64);    // FFN1: 2048 blocks
    dim3 gf2 (M / 64, D_MODEL / 64);   // FFN2: 512 blocks
    int nAttnBlk = BSZ * N_HEADS * (SEQ / 64);

    const size_t WSTRIDE = (size_t)D_MODEL * D_MODEL;
    for (int L = 0; L < N_LAYERS; L++) {
        const float* sW = self_W + (size_t)L * 4 * WSTRIDE;
        const float* sb = self_b + (size_t)L * 4 * D_MODEL;
        const float* eW = enc_W  + (size_t)L * 4 * WSTRIDE;
        const float* eb = enc_b  + (size_t)L * 4 * D_MODEL;
        const float* g  = ln_g   + (size_t)L * 3 * D_MODEL;
        const float* bs = ln_b   + (size_t)L * 3 * D_MODEL;

        // ---- self attention ----
        gemm_mfma_kernel<1,0,1><<<gqkv, blk, 0, stream>>>(xb, xb, sW, sb, bQ, bK, bV, M, D_MODEL, D_MODEL);
        attn_kernel<1><<<dim3(nAttnBlk), blk, 0, stream>>>(bQ, bK, bV, dec, listEnc, cntEnc, anyPadDec, bD, SEQ, SEQ);
        gemm_mfma_kernel<0,0,0><<<gp, blk, 0, stream>>>(bD, nullptr, sW + 3 * WSTRIDE, sb + 3 * D_MODEL, bA, nullptr, nullptr, M, D_MODEL, D_MODEL);
        ln_residual_kernel<1><<<dim3(M / 4), blk, 0, stream>>>(bA, x, g + 0 * D_MODEL, bs + 0 * D_MODEL, x, xb);

        // ---- cross attention (Q from x, K/V from encoder outputs; one merged launch) ----
        gemm_mfma_kernel<1,0,1><<<gqkv, blk, 0, stream>>>(xb, encb, eW, eb, bQ, bK, bV, M, D_MODEL, D_MODEL);
        attn_kernel<0><<<dim3(nAttnBlk), blk, 0, stream>>>(bQ, bK, bV, enc_ids, listEnc, cntEnc, anyPadDec, bD, SEQ, SEQ);
        gemm_mfma_kernel<0,0,0><<<gp, blk, 0, stream>>>(bD, nullptr, eW + 3 * WSTRIDE, eb + 3 * D_MODEL, bA, nullptr, nullptr, M, D_MODEL, D_MODEL);
        ln_residual_kernel<1><<<dim3(M / 4), blk, 0, stream>>>(bA, x, g + 1 * D_MODEL, bs + 1 * D_MODEL, x, xb);

        // ---- FFN ----
        gemm_mfma_kernel<1,1,0><<<gf1, blk, 0, stream>>>(xb, nullptr, W1 + (size_t)L * D_MODEL * D_FF, b1 + (size_t)L * D_FF,    bH, nullptr, nullptr, M, D_FF,    D_MODEL);
        gemm_mfma_kernel<0,0,0><<<gf2, blk, 0, stream>>>(bH, nullptr, W2 + (size_t)L * D_FF * D_MODEL, b2 + (size_t)L * D_MODEL, bA, nullptr, nullptr, M, D_MODEL, D_FF);
        float* lnout = (L == N_LAYERS - 1) ? out : x;
        ln_residual_kernel<1><<<dim3(M / 4), blk, 0, stream>>>(bA, x, g + 2 * D_MODEL, bs + 2 * D_MODEL, lnout, xb);
    }
}

// Round 7
// 619.597 us; speedup vs baseline: 13.2951x; 1.2766x over previous
//
#include <hip/hip_runtime.h>
#include <math.h>

#define D_MODEL 512
#define N_HEADS 8
#define D_KH    64
#define D_FF    2048
#define N_LAYERS 4
#define BSZ     4
#define SEQ     1024

typedef __attribute__((ext_vector_type(8))) __bf16 bf16x8;
typedef __attribute__((ext_vector_type(8))) short  s16x8;
typedef __attribute__((ext_vector_type(4))) float  f32x4;

union BF8 { s16x8 s; bf16x8 b; };

static __device__ inline unsigned short f2b(float f) {
    unsigned u = __float_as_uint(f);
    unsigned r = (u + 0x7fffu + ((u >> 16) & 1u)) >> 16;   // RNE
    return (unsigned short)r;
}

// async global->LDS 16B: lds dest = wave-uniform base + lane*16; global src per-lane.
static __device__ __forceinline__ void async16(const unsigned short* g, unsigned short* l) {
    __builtin_amdgcn_global_load_lds((const __attribute__((address_space(1))) unsigned int*)g,
                                     (__attribute__((address_space(3))) unsigned int*)l, 16, 0, 0);
}

// ---------------- embedding + sinusoid positional encoding (fp32 + bf16 shadow) -----
__global__ void embed_kernel(const int* __restrict__ dec, const float* __restrict__ emb,
                             float* __restrict__ x, unsigned short* __restrict__ xb) {
    int idx = blockIdx.x * blockDim.x + threadIdx.x;
    int d  = idx % D_MODEL;
    int bs = idx / D_MODEL;
    int s  = bs % SEQ;
    int tok = dec[bs];
    float pos = (float)(s + 5);
    float e = (float)(d & ~1) / (float)D_MODEL;
    float denom = powf(10000.0f, e);
    float ang = pos / denom;
    float pe = (d & 1) ? cosf(ang) : sinf(ang);
    float v = emb[(size_t)tok * D_MODEL + d] + pe;
    x[idx] = v;
    xb[idx] = f2b(v);
}

// ---------------- fp32 -> bf16 bulk convert (enc_out, once) -------------------------
__global__ void cvt_bf16_kernel(const float* __restrict__ in, unsigned short* __restrict__ outp, int n4) {
    int i = blockIdx.x * blockDim.x + threadIdx.x;
    if (i < n4) {
        float4 f = ((const float4*)in)[i];
        ushort4 h;
        h.x = f2b(f.x); h.y = f2b(f.y); h.z = f2b(f.z); h.w = f2b(f.w);
        ((ushort4*)outp)[i] = h;
    }
}

// ---------------- weight transpose+convert: src[K][N] fp32 -> dst[N][K] bf16 --------
__global__ void wt_kernel(const float* __restrict__ src, unsigned short* __restrict__ dst,
                          int K, int N) {
    __shared__ unsigned short Tb[64][72];
    int k0 = blockIdx.x * 64, n0 = blockIdx.y * 64;
    size_t zoff = (size_t)blockIdx.z * K * N;
    src += zoff; dst += zoff;
    int t = threadIdx.x;
    int kr = t & 63, sg = t >> 6;
    const float* sp = src + (size_t)(k0 + kr) * N + n0 + sg * 16;
    #pragma unroll
    for (int j = 0; j < 4; j++) {
        float4 f = *(const float4*)(sp + 4 * j);
        Tb[sg * 16 + 4 * j + 0][kr] = f2b(f.x);
        Tb[sg * 16 + 4 * j + 1][kr] = f2b(f.y);
        Tb[sg * 16 + 4 * j + 2][kr] = f2b(f.z);
        Tb[sg * 16 + 4 * j + 3][kr] = f2b(f.w);
    }
    __syncthreads();
    unsigned short* dp = dst + (size_t)(n0 + kr) * K + k0 + sg * 16;
    *(s16x8*)(dp)     = *(const s16x8*)&Tb[kr][sg * 16];
    *(s16x8*)(dp + 8) = *(const s16x8*)&Tb[kr][sg * 16 + 8];
}

// ---------------- mask prep: enc pad-key compaction + dec pad-tile flags ------------
__global__ void prep_kernel(const int* __restrict__ dec, const int* __restrict__ enc,
                            int* __restrict__ cntEnc, int* __restrict__ listEnc,
                            int* __restrict__ anyPadDec) {
    int b = blockIdx.x;
    int lane = threadIdx.x;
    int base = 0;
    for (int c0 = 0; c0 < SEQ; c0 += 64) {
        bool z = (enc[b * SEQ + c0 + lane] == 0);
        unsigned long long mask = __ballot(z);
        int pre = __popcll(mask & ((1ull << lane) - 1ull));
        if (z) listEnc[b * SEQ + base + pre] = c0 + lane;
        base += __popcll(mask);
    }
    if (lane == 0) cntEnc[b] = base;
    for (int c0 = 0; c0 < SEQ; c0 += 64) {
        bool z = (dec[b * SEQ + c0 + lane] == 0);
        unsigned long long mask = __ballot(z);
        if (lane == 0) anyPadDec[b * (SEQ / 64) + (c0 >> 6)] = (mask != 0ull) ? 1 : 0;
    }
}

// ---------------- bf16 MFMA GEMM, global_load_lds + XOR swizzle, double-buffered ----
// C[M,N] = A[M,K](bf16) @ Wt^T + bias, Wt is [N][K] bf16 (pre-transposed).
// BM=128, BN=64, BK=64; 4 waves, wave tile 32x64 (2x4 frags, 16 MFMA/ktile).
// LDS linear [row][64] elems; swizzle: stored[r][e] = logical[r][e ^ 8*(r&7)]
// (inverse applied on global src; ds_read applies same XOR -> 2-way banks = free).
template<int OUTBF16, int RELU, int QKV>
__launch_bounds__(256, 3)
__global__ void gemm_lds_kernel(const unsigned short* __restrict__ A, const unsigned short* __restrict__ A1,
                                const unsigned short* __restrict__ Wt, const float* __restrict__ bias,
                                void* __restrict__ C_, void* __restrict__ C1, void* __restrict__ C2,
                                int M, int N, int K) {
    __shared__ unsigned short lds[2][12288];   // [A 128x64 | B 64x64] x 2 buf = 48KB
    int m0 = blockIdx.x * 128, n0;
    if (QKV) {
        int j = blockIdx.y >> 3;
        n0 = (int)(blockIdx.y & 7) * 64;
        Wt += (size_t)j * (D_MODEL * D_MODEL);
        bias += j * D_MODEL;
        if (j) A = A1;
        if (j == 1) C_ = C1; else if (j == 2) C_ = C2;
    } else n0 = blockIdx.y * 64;

    int t = threadIdx.x, w = t >> 6, lane = t & 63;
    int g = lane >> 4, c = lane & 15;
    int l3 = lane >> 3, l7 = lane & 7;
    int srcoff = 8 * (l7 ^ l3);                 // inverse-swizzled elem col within k-tile

    const unsigned short* Abase = A  + (size_t)m0 * K;
    const unsigned short* Bbase = Wt + (size_t)n0 * K;

    f32x4 acc[2][4];
    #pragma unroll
    for (int mi = 0; mi < 2; mi++)
        #pragma unroll
        for (int nj = 0; nj < 4; nj++) acc[mi][nj] = (f32x4){0.f, 0.f, 0.f, 0.f};

#define STAGE(BUF, KT) do {                                                         \
        unsigned short* Lb_ = &lds[BUF][0];                                         \
        int k0_ = (KT) * 64;                                                        \
        _Pragma("unroll")                                                           \
        for (int i_ = 0; i_ < 4; i_++) {                                            \
            int q_ = w * 4 + i_;                                                    \
            async16(Abase + (size_t)(q_ * 8 + l3) * K + k0_ + srcoff, Lb_ + q_ * 512); \
        }                                                                           \
        _Pragma("unroll")                                                           \
        for (int i_ = 0; i_ < 2; i_++) {                                            \
            int q_ = w * 2 + i_;                                                    \
            async16(Bbase + (size_t)(q_ * 8 + l3) * K + k0_ + srcoff, Lb_ + 8192 + q_ * 512); \
        }                                                                           \
    } while (0)

    int nt = K >> 6;
    STAGE(0, 0);
    __syncthreads();                             // drains vmcnt: buf0 ready
    for (int kt = 0; kt < nt; kt++) {
        int cur = kt & 1;
        if (kt + 1 < nt) STAGE(cur ^ 1, kt + 1); // in flight across this tile's MFMA
        const unsigned short* Lb = &lds[cur][0];
        BF8 a[2][2], b[2][4];
        #pragma unroll
        for (int kk = 0; kk < 2; kk++) {
            int xo = (kk * 32 + g * 8) ^ ((c & 7) * 8);
            #pragma unroll
            for (int mi = 0; mi < 2; mi++)
                a[kk][mi].s = *(const s16x8*)&Lb[(w * 32 + mi * 16 + c) * 64 + xo];
            #pragma unroll
            for (int nj = 0; nj < 4; nj++)
                b[kk][nj].s = *(const s16x8*)&Lb[8192 + (nj * 16 + c) * 64 + xo];
        }
        #pragma unroll
        for (int kk = 0; kk < 2; kk++)
            #pragma unroll
            for (int mi = 0; mi < 2; mi++)
                #pragma unroll
                for (int nj = 0; nj < 4; nj++)
                    acc[mi][nj] = __builtin_amdgcn_mfma_f32_16x16x32_bf16(a[kk][mi].b, b[kk][nj].b, acc[mi][nj], 0, 0, 0);
        __syncthreads();                         // reads done + next buf staged
    }
#undef STAGE

    #pragma unroll
    for (int mi = 0; mi < 2; mi++) {
        #pragma unroll
        for (int nj = 0; nj < 4; nj++) {
            #pragma unroll
            for (int r = 0; r < 4; r++) {
                int row = m0 + w * 32 + mi * 16 + g * 4 + r;
                int col = n0 + nj * 16 + c;
                float v = acc[mi][nj][r] + bias[col];
                if (RELU) v = fmaxf(v, 0.0f);
                if (OUTBF16) ((unsigned short*)C_)[(size_t)row * N + col] = f2b(v);
                else         ((float*)C_)[(size_t)row * N + col] = v;
            }
        }
    }
}

// ---------------- MFMA bf16 flash attention, balanced + reg-prefetched --------------
#define RS 72
template<int MODE>
__global__ void attn_kernel(const unsigned short* __restrict__ Q, const unsigned short* __restrict__ K,
                            const unsigned short* __restrict__ V, const int* __restrict__ ids,
                            const int* __restrict__ list, const int* __restrict__ cnt,
                            const int* __restrict__ anyPad,
                            unsigned short* __restrict__ O_, int Sq, int Sk) {
    __shared__ unsigned short Kl[64][RS];
    __shared__ unsigned short Vt[64][RS];
    __shared__ unsigned short Ps[4][16][RS];
    __shared__ short act[16];
    __shared__ int nActS;

    int blk = blockIdx.x;
    int qt, bh;
    if (MODE) {
        int hi = blk >> 8, pair = blk & 255;
        bh = pair >> 3;
        int qtp = pair & 7;
        qt = hi ? (15 - qtp) : qtp;
    } else {
        qt = blk & 15;
        bh = blk >> 4;
    }
    int h = bh % N_HEADS;
    int b = bh / N_HEADS;
    int qbase = qt * 64;
    int t = threadIdx.x;
    int w = t >> 6, lane = t & 63;
    int g = lane >> 4, c = lane & 15;

    BF8 qf[2];
    {
        int qrow = qbase + w * 16 + c;
        const unsigned short* qp = Q + ((size_t)(b * Sq + qrow)) * D_MODEL + h * D_KH;
        qf[0].s = *(const s16x8*)(qp + 8 * g);
        qf[1].s = *(const s16x8*)(qp + 8 * g + 32);
    }

    int nk = 0;
    bool gathered = false;
    if (!MODE) {
        nk = cnt[b];
        gathered = (nk > 0);
    }

    if (t == 0) {
        int n = 0;
        if (MODE) {
            for (int kt2 = 0; kt2 < (Sk >> 6); kt2++)
                if (kt2 <= qt || anyPad[b * (Sk >> 6) + kt2]) act[n++] = (short)kt2;
        } else {
            int tt = gathered ? ((nk + 63) >> 6) : (Sk >> 6);
            for (int kt2 = 0; kt2 < tt; kt2++) act[n++] = (short)kt2;
        }
        nActS = n;
    }
    __syncthreads();
    int nAct = nActS;

    float m[4], l[4];
    f32x4 Oacc[4];
    #pragma unroll
    for (int r = 0; r < 4; r++) { m[r] = -INFINITY; l[r] = 0.0f; }
    #pragma unroll
    for (int ds = 0; ds < 4; ds++) Oacc[ds] = (f32x4){0.f, 0.f, 0.f, 0.f};

    s16x8 kreg0, kreg1, vreg0, vreg1;
    int kr0 = t >> 3,        ks0 = t & 7;
    int kr1 = (t + 256) >> 3, ks1 = (t + 256) & 7;

#define LOADT(KT) do {                                                                \
        int k0_ = (KT) * 64;                                                          \
        int krow0 = k0_ + kr0, krow1 = k0_ + kr1;                                     \
        if (gathered) {                                                               \
            krow0 = list[b * Sk + (krow0 < nk ? krow0 : nk - 1)];                     \
            krow1 = list[b * Sk + (krow1 < nk ? krow1 : nk - 1)];                     \
        }                                                                             \
        kreg0 = *(const s16x8*)(K + ((size_t)(b * Sk + krow0)) * D_MODEL + h * D_KH + ks0 * 8); \
        kreg1 = *(const s16x8*)(K + ((size_t)(b * Sk + krow1)) * D_MODEL + h * D_KH + ks1 * 8); \
        int li = k0_ + lane, vrow = li;                                               \
        if (gathered) vrow = list[b * Sk + (li < nk ? li : nk - 1)];                  \
        const unsigned short* vp = V + ((size_t)(b * Sk + vrow)) * D_MODEL + h * D_KH + w * 16; \
        vreg0 = *(const s16x8*)(vp);                                                  \
        vreg1 = *(const s16x8*)(vp + 8);                                              \
    } while (0)

    LOADT(act[0]);
    for (int i = 0; i < nAct; i++) {
        int k0 = (int)act[i] * 64;
        __syncthreads();
        *(s16x8*)&Kl[kr0][ks0 * 8] = kreg0;
        *(s16x8*)&Kl[kr1][ks1 * 8] = kreg1;
        #pragma unroll
        for (int j = 0; j < 8; j++) Vt[w * 16 + j][lane] = ((unsigned short*)&vreg0)[j];
        #pragma unroll
        for (int j = 0; j < 8; j++) Vt[w * 16 + 8 + j][lane] = ((unsigned short*)&vreg1)[j];
        __syncthreads();
        if (i + 1 < nAct) LOADT(act[i + 1]);

        f32x4 S[4];
        #pragma unroll
        for (int sub = 0; sub < 4; sub++) {
            BF8 b0, b1;
            b0.s = *(const s16x8*)&Kl[sub * 16 + c][8 * g];
            b1.s = *(const s16x8*)&Kl[sub * 16 + c][8 * g + 32];
            f32x4 s = (f32x4){0.f, 0.f, 0.f, 0.f};
            s = __builtin_amdgcn_mfma_f32_16x16x32_bf16(qf[0].b, b0.b, s, 0, 0, 0);
            s = __builtin_amdgcn_mfma_f32_16x16x32_bf16(qf[1].b, b1.b, s, 0, 0, 0);
            S[sub] = s;
        }

        #pragma unroll
        for (int sub = 0; sub < 4; sub++) {
            int k = k0 + sub * 16 + c;
            bool pad;
            if (MODE) pad = (ids[b * Sk + k] == 0);
            else      pad = gathered ? (k < nk) : false;
            #pragma unroll
            for (int r = 0; r < 4; r++) {
                bool att;
                if (MODE) {
                    int qrow = qbase + w * 16 + g * 4 + r;
                    att = pad || (k <= qrow);
                } else att = pad;
                S[sub][r] = att ? S[sub][r] * 0.125f : -1e9f;
            }
        }

        #pragma unroll
        for (int r = 0; r < 4; r++) {
            float mx = fmaxf(fmaxf(S[0][r], S[1][r]), fmaxf(S[2][r], S[3][r]));
            #pragma unroll
            for (int o = 8; o > 0; o >>= 1) mx = fmaxf(mx, __shfl_xor(mx, o));
            float mn = fmaxf(m[r], mx);
            float sc = __expf(m[r] - mn);
            float lsum = 0.f;
            #pragma unroll
            for (int sub = 0; sub < 4; sub++) {
                float p = __expf(S[sub][r] - mn);
                S[sub][r] = p;
                lsum += p;
            }
            #pragma unroll
            for (int o = 8; o > 0; o >>= 1) lsum += __shfl_xor(lsum, o);
            l[r] = l[r] * sc + lsum;
            m[r] = mn;
            #pragma unroll
            for (int ds = 0; ds < 4; ds++) Oacc[ds][r] *= sc;
        }

        #pragma unroll
        for (int sub = 0; sub < 4; sub++)
            #pragma unroll
            for (int r = 0; r < 4; r++)
                Ps[w][g * 4 + r][sub * 16 + c] = f2b(S[sub][r]);

        #pragma unroll
        for (int kk = 0; kk < 2; kk++) {
            BF8 pa;
            pa.s = *(const s16x8*)&Ps[w][c][8 * g + kk * 32];
            #pragma unroll
            for (int ds = 0; ds < 4; ds++) {
                BF8 vb;
                vb.s = *(const s16x8*)&Vt[ds * 16 + c][8 * g + kk * 32];
                Oacc[ds] = __builtin_amdgcn_mfma_f32_16x16x32_bf16(pa.b, vb.b, Oacc[ds], 0, 0, 0);
            }
        }
    }
#undef LOADT

    #pragma unroll
    for (int r = 0; r < 4; r++) {
        float inv = 1.0f / l[r];
        int qrow = qbase + w * 16 + g * 4 + r;
        unsigned short* op = O_ + ((size_t)(b * Sq + qrow)) * D_MODEL + h * D_KH;
        #pragma unroll
        for (int ds = 0; ds < 4; ds++)
            op[ds * 16 + c] = f2b(Oacc[ds][r] * inv);
    }
}

// ---------------- layernorm(f + h), fp32 out + optional bf16 shadow -----------------
template<int WRITEB>
__global__ void ln_residual_kernel(const float* __restrict__ f, const float* __restrict__ h,
                                   const float* __restrict__ g, const float* __restrict__ bb,
                                   float* __restrict__ out, unsigned short* __restrict__ outb) {
    int row  = blockIdx.x * 4 + threadIdx.x / 64;
    int lane = threadIdx.x % 64;
    const float* fr = f + (size_t)row * D_MODEL;
    const float* hr = h + (size_t)row * D_MODEL;
    float v[8];
    float s = 0.f;
    #pragma unroll
    for (int i = 0; i < 8; i++) {
        v[i] = fr[lane + i * 64] + hr[lane + i * 64];
        s += v[i];
    }
    #pragma unroll
    for (int o = 32; o > 0; o >>= 1) s += __shfl_xor(s, o);
    float mu = s * (1.0f / 512.0f);
    float ss = 0.f;
    #pragma unroll
    for (int i = 0; i < 8; i++) { float d = v[i] - mu; ss += d * d; }
    #pragma unroll
    for (int o = 32; o > 0; o >>= 1) ss += __shfl_xor(ss, o);
    float var = ss * (1.0f / 512.0f);
    float inv = 1.0f / sqrtf(var + 1e-6f);
    #pragma unroll
    for (int i = 0; i < 8; i++) {
        int d = lane + i * 64;
        float o2 = g[d] * (v[i] - mu) * inv + bb[d];
        out[(size_t)row * D_MODEL + d] = o2;
        if (WRITEB) outb[(size_t)row * D_MODEL + d] = f2b(o2);
    }
}

extern "C" void kernel_launch(void* const* d_in, const int* in_sizes, int n_in,
                              void* d_out, int out_size, void* d_ws, size_t ws_size,
                              hipStream_t stream) {
    const int*   dec     = (const int*)d_in[0];
    const int*   enc_ids = (const int*)d_in[1];
    const float* enc_out = (const float*)d_in[2];
    const float* emb     = (const float*)d_in[3];
    const float* self_W  = (const float*)d_in[4];
    const float* self_b  = (const float*)d_in[5];
    const float* enc_W   = (const float*)d_in[6];
    const float* enc_b   = (const float*)d_in[7];
    const float* W1      = (const float*)d_in[8];
    const float* b1      = (const float*)d_in[9];
    const float* W2      = (const float*)d_in[10];
    const float* b2      = (const float*)d_in[11];
    const float* ln_g    = (const float*)d_in[12];
    const float* ln_b    = (const float*)d_in[13];
    float* out = (float*)d_out;

    const size_t NTOK = (size_t)BSZ * SEQ;      // 4096
    // ws layout (MB): x 8 | bA 8 | xb 4 | encb 4 | region 16 (QKVD / H) | wt 32 | masks
    float* x  = (float*)d_ws;
    float* bA = x + NTOK * D_MODEL;
    unsigned short* xb   = (unsigned short*)(bA + NTOK * D_MODEL);
    unsigned short* encb = xb + NTOK * D_MODEL;
    unsigned short* bQ = encb + NTOK * D_MODEL;
    unsigned short* bK = bQ + NTOK * D_MODEL;
    unsigned short* bV = bK + NTOK * D_MODEL;
    unsigned short* bD = bV + NTOK * D_MODEL;
    unsigned short* bH = bQ;                    // 4096*2048 bf16 aliases bQ..bD
    unsigned short* wtS  = bD + NTOK * D_MODEL;                 // 4L*4*512*512 bf16 (8MB)
    unsigned short* wtE  = wtS + (size_t)N_LAYERS * 4 * D_MODEL * D_MODEL;
    unsigned short* wtF1 = wtE + (size_t)N_LAYERS * 4 * D_MODEL * D_MODEL;
    unsigned short* wtF2 = wtF1 + (size_t)N_LAYERS * D_MODEL * D_FF;
    int* cntEnc    = (int*)(wtF2 + (size_t)N_LAYERS * D_FF * D_MODEL);
    int* anyPadDec = cntEnc + BSZ;
    int* listEnc   = anyPadDec + BSZ * (SEQ / 64);

    dim3 blk(256);
    embed_kernel<<<dim3((unsigned)(NTOK * D_MODEL / 256)), blk, 0, stream>>>(dec, emb, x, xb);
    cvt_bf16_kernel<<<dim3((unsigned)(NTOK * D_MODEL / 4 / 256)), blk, 0, stream>>>(enc_out, encb, (int)(NTOK * D_MODEL / 4));
    prep_kernel<<<dim3(BSZ), dim3(64), 0, stream>>>(dec, enc_ids, cntEnc, listEnc, anyPadDec);
    wt_kernel<<<dim3(8, 8, 16), blk, 0, stream>>>(self_W, wtS, D_MODEL, D_MODEL);
    wt_kernel<<<dim3(8, 8, 16), blk, 0, stream>>>(enc_W,  wtE, D_MODEL, D_MODEL);
    wt_kernel<<<dim3(8, 32, 4), blk, 0, stream>>>(W1, wtF1, D_MODEL, D_FF);
    wt_kernel<<<dim3(32, 8, 4), blk, 0, stream>>>(W2, wtF2, D_FF, D_MODEL);

    int M = (int)NTOK;
    dim3 gqkv(M / 128, 24);            // merged QKV: 768 blocks
    dim3 gp  (M / 128, D_MODEL / 64);  // proj: 256 blocks
    dim3 gf1 (M / 128, D_FF / 64);     // FFN1: 1024 blocks
    dim3 gf2 (M / 128, D_MODEL / 64);  // FFN2: 256 blocks
    int nAttnBlk = BSZ * N_HEADS * (SEQ / 64);

    const size_t WT = (size_t)D_MODEL * D_MODEL;
    for (int L = 0; L < N_LAYERS; L++) {
        const unsigned short* sWt = wtS + (size_t)L * 4 * WT;
        const unsigned short* eWt = wtE + (size_t)L * 4 * WT;
        const float* sb = self_b + (size_t)L * 4 * D_MODEL;
        const float* eb = enc_b  + (size_t)L * 4 * D_MODEL;
        const float* g  = ln_g   + (size_t)L * 3 * D_MODEL;
        const float* bs = ln_b   + (size_t)L * 3 * D_MODEL;

        // ---- self attention ----
        gemm_lds_kernel<1,0,1><<<gqkv, blk, 0, stream>>>(xb, xb, sWt, sb, bQ, bK, bV, M, D_MODEL, D_MODEL);
        attn_kernel<1><<<dim3(nAttnBlk), blk, 0, stream>>>(bQ, bK, bV, dec, listEnc, cntEnc, anyPadDec, bD, SEQ, SEQ);
        gemm_lds_kernel<0,0,0><<<gp, blk, 0, stream>>>(bD, nullptr, sWt + 3 * WT, sb + 3 * D_MODEL, bA, nullptr, nullptr, M, D_MODEL, D_MODEL);
        ln_residual_kernel<1><<<dim3(M / 4), blk, 0, stream>>>(bA, x, g + 0 * D_MODEL, bs + 0 * D_MODEL, x, xb);

        // ---- cross attention ----
        gemm_lds_kernel<1,0,1><<<gqkv, blk, 0, stream>>>(xb, encb, eWt, eb, bQ, bK, bV, M, D_MODEL, D_MODEL);
        attn_kernel<0><<<dim3(nAttnBlk), blk, 0, stream>>>(bQ, bK, bV, enc_ids, listEnc, cntEnc, anyPadDec, bD, SEQ, SEQ);
        gemm_lds_kernel<0,0,0><<<gp, blk, 0, stream>>>(bD, nullptr, eWt + 3 * WT, eb + 3 * D_MODEL, bA, nullptr, nullptr, M, D_MODEL, D_MODEL);
        ln_residual_kernel<1><<<dim3(M / 4), blk, 0, stream>>>(bA, x, g + 1 * D_MODEL, bs + 1 * D_MODEL, x, xb);

        // ---- FFN ----
        gemm_lds_kernel<1,1,0><<<gf1, blk, 0, stream>>>(xb, nullptr, wtF1 + (size_t)L * D_MODEL * D_FF, b1 + (size_t)L * D_FF,    bH, nullptr, nullptr, M, D_FF,    D_MODEL);
        gemm_lds_kernel<0,0,0><<<gf2, blk, 0, stream>>>(bH, nullptr, wtF2 + (size_t)L * D_FF * D_MODEL, b2 + (size_t)L * D_MODEL, bA, nullptr, nullptr, M, D_MODEL, D_FF);
        float* lnout = (L == N_LAYERS - 1) ? out : x;
        ln_residual_kernel<1><<<dim3(M / 4), blk, 0, stream>>>(bA, x, g + 2 * D_MODEL, bs + 2 * D_MODEL, lnout, xb);
    }
}

// Round 8
// 606.827 us; speedup vs baseline: 13.5748x; 1.0210x over previous
//
#include <hip/hip_runtime.h>
#include <math.h>

#define D_MODEL 512
#define N_HEADS 8
#define D_KH    64
#define D_FF    2048
#define N_LAYERS 4
#define BSZ     4
#define SEQ     1024

typedef __attribute__((ext_vector_type(8))) __bf16 bf16x8;
typedef __attribute__((ext_vector_type(8))) short  s16x8;
typedef __attribute__((ext_vector_type(4))) float  f32x4;

union BF8 { s16x8 s; bf16x8 b; };

static __device__ inline unsigned short f2b(float f) {
    unsigned u = __float_as_uint(f);
    unsigned r = (u + 0x7fffu + ((u >> 16) & 1u)) >> 16;   // RNE
    return (unsigned short)r;
}

// async global->LDS 16B: lds dest = wave-uniform base + lane*16; global src per-lane.
static __device__ __forceinline__ void async16(const unsigned short* g, unsigned short* l) {
    __builtin_amdgcn_global_load_lds((const __attribute__((address_space(1))) unsigned int*)g,
                                     (__attribute__((address_space(3))) unsigned int*)l, 16, 0, 0);
}

// ---------------- embedding + sinusoid positional encoding (fp32 + bf16 shadow) -----
__global__ void embed_kernel(const int* __restrict__ dec, const float* __restrict__ emb,
                             float* __restrict__ x, unsigned short* __restrict__ xb) {
    int idx = blockIdx.x * blockDim.x + threadIdx.x;
    int d  = idx % D_MODEL;
    int bs = idx / D_MODEL;
    int s  = bs % SEQ;
    int tok = dec[bs];
    float pos = (float)(s + 5);
    float e = (float)(d & ~1) / (float)D_MODEL;
    float denom = powf(10000.0f, e);
    float ang = pos / denom;
    float pe = (d & 1) ? cosf(ang) : sinf(ang);
    float v = emb[(size_t)tok * D_MODEL + d] + pe;
    x[idx] = v;
    xb[idx] = f2b(v);
}

// ---------------- fp32 -> bf16 bulk convert (enc_out, once) -------------------------
__global__ void cvt_bf16_kernel(const float* __restrict__ in, unsigned short* __restrict__ outp, int n4) {
    int i = blockIdx.x * blockDim.x + threadIdx.x;
    if (i < n4) {
        float4 f = ((const float4*)in)[i];
        ushort4 h;
        h.x = f2b(f.x); h.y = f2b(f.y); h.z = f2b(f.z); h.w = f2b(f.w);
        ((ushort4*)outp)[i] = h;
    }
}

// ---------------- weight transpose+convert: src[K][N] fp32 -> dst[N][K] bf16 --------
__global__ void wt_kernel(const float* __restrict__ src, unsigned short* __restrict__ dst,
                          int K, int N) {
    __shared__ unsigned short Tb[64][72];
    int k0 = blockIdx.x * 64, n0 = blockIdx.y * 64;
    size_t zoff = (size_t)blockIdx.z * K * N;
    src += zoff; dst += zoff;
    int t = threadIdx.x;
    int kr = t & 63, sg = t >> 6;
    const float* sp = src + (size_t)(k0 + kr) * N + n0 + sg * 16;
    #pragma unroll
    for (int j = 0; j < 4; j++) {
        float4 f = *(const float4*)(sp + 4 * j);
        Tb[sg * 16 + 4 * j + 0][kr] = f2b(f.x);
        Tb[sg * 16 + 4 * j + 1][kr] = f2b(f.y);
        Tb[sg * 16 + 4 * j + 2][kr] = f2b(f.z);
        Tb[sg * 16 + 4 * j + 3][kr] = f2b(f.w);
    }
    __syncthreads();
    unsigned short* dp = dst + (size_t)(n0 + kr) * K + k0 + sg * 16;
    *(s16x8*)(dp)     = *(const s16x8*)&Tb[kr][sg * 16];
    *(s16x8*)(dp + 8) = *(const s16x8*)&Tb[kr][sg * 16 + 8];
}

// ---------------- mask prep: enc pad-key compaction + dec pad-tile flags ------------
__global__ void prep_kernel(const int* __restrict__ dec, const int* __restrict__ enc,
                            int* __restrict__ cntEnc, int* __restrict__ listEnc,
                            int* __restrict__ anyPadDec) {
    int b = blockIdx.x;
    int lane = threadIdx.x;
    int base = 0;
    for (int c0 = 0; c0 < SEQ; c0 += 64) {
        bool z = (enc[b * SEQ + c0 + lane] == 0);
        unsigned long long mask = __ballot(z);
        int pre = __popcll(mask & ((1ull << lane) - 1ull));
        if (z) listEnc[b * SEQ + base + pre] = c0 + lane;
        base += __popcll(mask);
    }
    if (lane == 0) cntEnc[b] = base;
    for (int c0 = 0; c0 < SEQ; c0 += 64) {
        bool z = (dec[b * SEQ + c0 + lane] == 0);
        unsigned long long mask = __ballot(z);
        if (lane == 0) anyPadDec[b * (SEQ / 64) + (c0 >> 6)] = (mask != 0ull) ? 1 : 0;
    }
}

// ---------------- bf16 MFMA GEMM 128x64, global_load_lds + XOR swizzle, dbuf --------
template<int OUTBF16, int RELU>
__launch_bounds__(256, 3)
__global__ void gemm_lds_kernel(const unsigned short* __restrict__ A,
                                const unsigned short* __restrict__ Wt, const float* __restrict__ bias,
                                void* __restrict__ C_, int M, int N, int K) {
    __shared__ unsigned short lds[2][12288];   // [A 128x64 | B 64x64] x 2 buf = 48KB
    int m0 = blockIdx.x * 128, n0 = blockIdx.y * 64;

    int t = threadIdx.x, w = t >> 6, lane = t & 63;
    int g = lane >> 4, c = lane & 15;
    int l3 = lane >> 3, l7 = lane & 7;
    int srcoff = 8 * (l7 ^ l3);                 // inverse-swizzled elem col within k-tile

    const unsigned short* Abase = A  + (size_t)m0 * K;
    const unsigned short* Bbase = Wt + (size_t)n0 * K;

    f32x4 acc[2][4];
    #pragma unroll
    for (int mi = 0; mi < 2; mi++)
        #pragma unroll
        for (int nj = 0; nj < 4; nj++) acc[mi][nj] = (f32x4){0.f, 0.f, 0.f, 0.f};

#define STAGE(BUF, KT) do {                                                         \
        unsigned short* Lb_ = &lds[BUF][0];                                         \
        int k0_ = (KT) * 64;                                                        \
        _Pragma("unroll")                                                           \
        for (int i_ = 0; i_ < 4; i_++) {                                            \
            int q_ = w * 4 + i_;                                                    \
            async16(Abase + (size_t)(q_ * 8 + l3) * K + k0_ + srcoff, Lb_ + q_ * 512); \
        }                                                                           \
        _Pragma("unroll")                                                           \
        for (int i_ = 0; i_ < 2; i_++) {                                            \
            int q_ = w * 2 + i_;                                                    \
            async16(Bbase + (size_t)(q_ * 8 + l3) * K + k0_ + srcoff, Lb_ + 8192 + q_ * 512); \
        }                                                                           \
    } while (0)

    int nt = K >> 6;
    STAGE(0, 0);
    __syncthreads();
    for (int kt = 0; kt < nt; kt++) {
        int cur = kt & 1;
        if (kt + 1 < nt) STAGE(cur ^ 1, kt + 1);
        const unsigned short* Lb = &lds[cur][0];
        BF8 a[2][2], b[2][4];
        #pragma unroll
        for (int kk = 0; kk < 2; kk++) {
            int xo = (kk * 32 + g * 8) ^ ((c & 7) * 8);
            #pragma unroll
            for (int mi = 0; mi < 2; mi++)
                a[kk][mi].s = *(const s16x8*)&Lb[(w * 32 + mi * 16 + c) * 64 + xo];
            #pragma unroll
            for (int nj = 0; nj < 4; nj++)
                b[kk][nj].s = *(const s16x8*)&Lb[8192 + (nj * 16 + c) * 64 + xo];
        }
        #pragma unroll
        for (int kk = 0; kk < 2; kk++)
            #pragma unroll
            for (int mi = 0; mi < 2; mi++)
                #pragma unroll
                for (int nj = 0; nj < 4; nj++)
                    acc[mi][nj] = __builtin_amdgcn_mfma_f32_16x16x32_bf16(a[kk][mi].b, b[kk][nj].b, acc[mi][nj], 0, 0, 0);
        __syncthreads();
    }
#undef STAGE

    #pragma unroll
    for (int mi = 0; mi < 2; mi++) {
        #pragma unroll
        for (int nj = 0; nj < 4; nj++) {
            #pragma unroll
            for (int r = 0; r < 4; r++) {
                int row = m0 + w * 32 + mi * 16 + g * 4 + r;
                int col = n0 + nj * 16 + c;
                float v = acc[mi][nj][r] + bias[col];
                if (RELU) v = fmaxf(v, 0.0f);
                if (OUTBF16) ((unsigned short*)C_)[(size_t)row * N + col] = f2b(v);
                else         ((float*)C_)[(size_t)row * N + col] = v;
            }
        }
    }
}

// ---------------- bf16 MFMA GEMM 128x128, wave tile 64x64 (LDS-traffic-optimal) -----
// 32.8 FLOP per LDS byte (1.5x the 128x64 tile). For QKV-merge and FFN1 (grid >=384).
template<int OUTBF16, int RELU, int QKV>
__launch_bounds__(256, 2)
__global__ void gemm128_kernel(const unsigned short* __restrict__ A, const unsigned short* __restrict__ A1,
                               const unsigned short* __restrict__ Wt, const float* __restrict__ bias,
                               void* __restrict__ C_, void* __restrict__ C1, void* __restrict__ C2,
                               int M, int N, int K) {
    __shared__ unsigned short lds[2][16384];   // [A 128x64 | B 128x64] x 2 buf = 64KB
    int m0 = blockIdx.x * 128, n0;
    if (QKV) {
        int j = blockIdx.y >> 2;               // N=512 per matrix -> 4 n-tiles of 128
        n0 = (int)(blockIdx.y & 3) * 128;
        Wt += (size_t)j * (D_MODEL * D_MODEL);
        bias += j * D_MODEL;
        if (j) A = A1;
        if (j == 1) C_ = C1; else if (j == 2) C_ = C2;
    } else n0 = blockIdx.y * 128;

    int t = threadIdx.x, w = t >> 6, lane = t & 63;
    int wm = w >> 1, wn = w & 1;               // 2x2 wave grid, wave tile 64x64
    int g = lane >> 4, c = lane & 15;
    int l3 = lane >> 3, l7 = lane & 7;
    int srcoff = 8 * (l7 ^ l3);

    const unsigned short* Abase = A  + (size_t)m0 * K;
    const unsigned short* Bbase = Wt + (size_t)n0 * K;

    f32x4 acc[4][4];
    #pragma unroll
    for (int mi = 0; mi < 4; mi++)
        #pragma unroll
        for (int nj = 0; nj < 4; nj++) acc[mi][nj] = (f32x4){0.f, 0.f, 0.f, 0.f};

#define STAGE128(BUF, KT) do {                                                      \
        unsigned short* Lb_ = &lds[BUF][0];                                         \
        int k0_ = (KT) * 64;                                                        \
        _Pragma("unroll")                                                           \
        for (int i_ = 0; i_ < 4; i_++) {                                            \
            int q_ = w * 4 + i_;                                                    \
            async16(Abase + (size_t)(q_ * 8 + l3) * K + k0_ + srcoff, Lb_ + q_ * 512); \
            async16(Bbase + (size_t)(q_ * 8 + l3) * K + k0_ + srcoff, Lb_ + 8192 + q_ * 512); \
        }                                                                           \
    } while (0)

    int nt = K >> 6;
    STAGE128(0, 0);
    __syncthreads();
    for (int kt = 0; kt < nt; kt++) {
        int cur = kt & 1;
        if (kt + 1 < nt) STAGE128(cur ^ 1, kt + 1);   // in flight across MFMA
        const unsigned short* Lb = &lds[cur][0];
        BF8 a[2][4], b[2][4];
        #pragma unroll
        for (int kk = 0; kk < 2; kk++) {
            int xo = (kk * 32 + g * 8) ^ ((c & 7) * 8);
            #pragma unroll
            for (int mi = 0; mi < 4; mi++)
                a[kk][mi].s = *(const s16x8*)&Lb[(wm * 64 + mi * 16 + c) * 64 + xo];
            #pragma unroll
            for (int nj = 0; nj < 4; nj++)
                b[kk][nj].s = *(const s16x8*)&Lb[8192 + (wn * 64 + nj * 16 + c) * 64 + xo];
        }
        #pragma unroll
        for (int kk = 0; kk < 2; kk++)
            #pragma unroll
            for (int mi = 0; mi < 4; mi++)
                #pragma unroll
                for (int nj = 0; nj < 4; nj++)
                    acc[mi][nj] = __builtin_amdgcn_mfma_f32_16x16x32_bf16(a[kk][mi].b, b[kk][nj].b, acc[mi][nj], 0, 0, 0);
        __syncthreads();
    }
#undef STAGE128

    #pragma unroll
    for (int mi = 0; mi < 4; mi++) {
        #pragma unroll
        for (int nj = 0; nj < 4; nj++) {
            #pragma unroll
            for (int r = 0; r < 4; r++) {
                int row = m0 + wm * 64 + mi * 16 + g * 4 + r;
                int col = n0 + wn * 64 + nj * 16 + c;
                float v = acc[mi][nj][r] + bias[col];
                if (RELU) v = fmaxf(v, 0.0f);
                if (OUTBF16) ((unsigned short*)C_)[(size_t)row * N + col] = f2b(v);
                else         ((float*)C_)[(size_t)row * N + col] = v;
            }
        }
    }
}

// ---------------- MFMA bf16 flash attention, balanced + reg-prefetched --------------
#define RS 72
template<int MODE>
__global__ void attn_kernel(const unsigned short* __restrict__ Q, const unsigned short* __restrict__ K,
                            const unsigned short* __restrict__ V, const int* __restrict__ ids,
                            const int* __restrict__ list, const int* __restrict__ cnt,
                            const int* __restrict__ anyPad,
                            unsigned short* __restrict__ O_, int Sq, int Sk) {
    __shared__ unsigned short Kl[64][RS];
    __shared__ unsigned short Vt[64][RS];
    __shared__ unsigned short Ps[4][16][RS];
    __shared__ short act[16];
    __shared__ int nActS;

    int blk = blockIdx.x;
    int qt, bh;
    if (MODE) {
        int hi = blk >> 8, pair = blk & 255;
        bh = pair >> 3;
        int qtp = pair & 7;
        qt = hi ? (15 - qtp) : qtp;
    } else {
        qt = blk & 15;
        bh = blk >> 4;
    }
    int h = bh % N_HEADS;
    int b = bh / N_HEADS;
    int qbase = qt * 64;
    int t = threadIdx.x;
    int w = t >> 6, lane = t & 63;
    int g = lane >> 4, c = lane & 15;

    BF8 qf[2];
    {
        int qrow = qbase + w * 16 + c;
        const unsigned short* qp = Q + ((size_t)(b * Sq + qrow)) * D_MODEL + h * D_KH;
        qf[0].s = *(const s16x8*)(qp + 8 * g);
        qf[1].s = *(const s16x8*)(qp + 8 * g + 32);
    }

    int nk = 0;
    bool gathered = false;
    if (!MODE) {
        nk = cnt[b];
        gathered = (nk > 0);
    }

    if (t == 0) {
        int n = 0;
        if (MODE) {
            for (int kt2 = 0; kt2 < (Sk >> 6); kt2++)
                if (kt2 <= qt || anyPad[b * (Sk >> 6) + kt2]) act[n++] = (short)kt2;
        } else {
            int tt = gathered ? ((nk + 63) >> 6) : (Sk >> 6);
            for (int kt2 = 0; kt2 < tt; kt2++) act[n++] = (short)kt2;
        }
        nActS = n;
    }
    __syncthreads();
    int nAct = nActS;

    float m[4], l[4];
    f32x4 Oacc[4];
    #pragma unroll
    for (int r = 0; r < 4; r++) { m[r] = -INFINITY; l[r] = 0.0f; }
    #pragma unroll
    for (int ds = 0; ds < 4; ds++) Oacc[ds] = (f32x4){0.f, 0.f, 0.f, 0.f};

    s16x8 kreg0, kreg1, vreg0, vreg1;
    int kr0 = t >> 3,        ks0 = t & 7;
    int kr1 = (t + 256) >> 3, ks1 = (t + 256) & 7;

#define LOADT(KT) do {                                                                \
        int k0_ = (KT) * 64;                                                          \
        int krow0 = k0_ + kr0, krow1 = k0_ + kr1;                                     \
        if (gathered) {                                                               \
            krow0 = list[b * Sk + (krow0 < nk ? krow0 : nk - 1)];                     \
            krow1 = list[b * Sk + (krow1 < nk ? krow1 : nk - 1)];                     \
        }                                                                             \
        kreg0 = *(const s16x8*)(K + ((size_t)(b * Sk + krow0)) * D_MODEL + h * D_KH + ks0 * 8); \
        kreg1 = *(const s16x8*)(K + ((size_t)(b * Sk + krow1)) * D_MODEL + h * D_KH + ks1 * 8); \
        int li = k0_ + lane, vrow = li;                                               \
        if (gathered) vrow = list[b * Sk + (li < nk ? li : nk - 1)];                  \
        const unsigned short* vp = V + ((size_t)(b * Sk + vrow)) * D_MODEL + h * D_KH + w * 16; \
        vreg0 = *(const s16x8*)(vp);                                                  \
        vreg1 = *(const s16x8*)(vp + 8);                                              \
    } while (0)

    LOADT(act[0]);
    for (int i = 0; i < nAct; i++) {
        int k0 = (int)act[i] * 64;
        __syncthreads();
        *(s16x8*)&Kl[kr0][ks0 * 8] = kreg0;
        *(s16x8*)&Kl[kr1][ks1 * 8] = kreg1;
        #pragma unroll
        for (int j = 0; j < 8; j++) Vt[w * 16 + j][lane] = ((unsigned short*)&vreg0)[j];
        #pragma unroll
        for (int j = 0; j < 8; j++) Vt[w * 16 + 8 + j][lane] = ((unsigned short*)&vreg1)[j];
        __syncthreads();
        if (i + 1 < nAct) LOADT(act[i + 1]);

        f32x4 S[4];
        #pragma unroll
        for (int sub = 0; sub < 4; sub++) {
            BF8 b0, b1;
            b0.s = *(const s16x8*)&Kl[sub * 16 + c][8 * g];
            b1.s = *(const s16x8*)&Kl[sub * 16 + c][8 * g + 32];
            f32x4 s = (f32x4){0.f, 0.f, 0.f, 0.f};
            s = __builtin_amdgcn_mfma_f32_16x16x32_bf16(qf[0].b, b0.b, s, 0, 0, 0);
            s = __builtin_amdgcn_mfma_f32_16x16x32_bf16(qf[1].b, b1.b, s, 0, 0, 0);
            S[sub] = s;
        }

        #pragma unroll
        for (int sub = 0; sub < 4; sub++) {
            int k = k0 + sub * 16 + c;
            bool pad;
            if (MODE) pad = (ids[b * Sk + k] == 0);
            else      pad = gathered ? (k < nk) : false;
            #pragma unroll
            for (int r = 0; r < 4; r++) {
                bool att;
                if (MODE) {
                    int qrow = qbase + w * 16 + g * 4 + r;
                    att = pad || (k <= qrow);
                } else att = pad;
                S[sub][r] = att ? S[sub][r] * 0.125f : -1e9f;
            }
        }

        #pragma unroll
        for (int r = 0; r < 4; r++) {
            float mx = fmaxf(fmaxf(S[0][r], S[1][r]), fmaxf(S[2][r], S[3][r]));
            #pragma unroll
            for (int o = 8; o > 0; o >>= 1) mx = fmaxf(mx, __shfl_xor(mx, o));
            float mn = fmaxf(m[r], mx);
            float sc = __expf(m[r] - mn);
            float lsum = 0.f;
            #pragma unroll
            for (int sub = 0; sub < 4; sub++) {
                float p = __expf(S[sub][r] - mn);
                S[sub][r] = p;
                lsum += p;
            }
            #pragma unroll
            for (int o = 8; o > 0; o >>= 1) lsum += __shfl_xor(lsum, o);
            l[r] = l[r] * sc + lsum;
            m[r] = mn;
            #pragma unroll
            for (int ds = 0; ds < 4; ds++) Oacc[ds][r] *= sc;
        }

        #pragma unroll
        for (int sub = 0; sub < 4; sub++)
            #pragma unroll
            for (int r = 0; r < 4; r++)
                Ps[w][g * 4 + r][sub * 16 + c] = f2b(S[sub][r]);

        #pragma unroll
        for (int kk = 0; kk < 2; kk++) {
            BF8 pa;
            pa.s = *(const s16x8*)&Ps[w][c][8 * g + kk * 32];
            #pragma unroll
            for (int ds = 0; ds < 4; ds++) {
                BF8 vb;
                vb.s = *(const s16x8*)&Vt[ds * 16 + c][8 * g + kk * 32];
                Oacc[ds] = __builtin_amdgcn_mfma_f32_16x16x32_bf16(pa.b, vb.b, Oacc[ds], 0, 0, 0);
            }
        }
    }
#undef LOADT

    #pragma unroll
    for (int r = 0; r < 4; r++) {
        float inv = 1.0f / l[r];
        int qrow = qbase + w * 16 + g * 4 + r;
        unsigned short* op = O_ + ((size_t)(b * Sq + qrow)) * D_MODEL + h * D_KH;
        #pragma unroll
        for (int ds = 0; ds < 4; ds++)
            op[ds * 16 + c] = f2b(Oacc[ds][r] * inv);
    }
}

// ---------------- layernorm(f + h), fp32 out + optional bf16 shadow -----------------
template<int WRITEB>
__global__ void ln_residual_kernel(const float* __restrict__ f, const float* __restrict__ h,
                                   const float* __restrict__ g, const float* __restrict__ bb,
                                   float* __restrict__ out, unsigned short* __restrict__ outb) {
    int row  = blockIdx.x * 4 + threadIdx.x / 64;
    int lane = threadIdx.x % 64;
    const float* fr = f + (size_t)row * D_MODEL;
    const float* hr = h + (size_t)row * D_MODEL;
    float v[8];
    float s = 0.f;
    #pragma unroll
    for (int i = 0; i < 8; i++) {
        v[i] = fr[lane + i * 64] + hr[lane + i * 64];
        s += v[i];
    }
    #pragma unroll
    for (int o = 32; o > 0; o >>= 1) s += __shfl_xor(s, o);
    float mu = s * (1.0f / 512.0f);
    float ss = 0.f;
    #pragma unroll
    for (int i = 0; i < 8; i++) { float d = v[i] - mu; ss += d * d; }
    #pragma unroll
    for (int o = 32; o > 0; o >>= 1) ss += __shfl_xor(ss, o);
    float var = ss * (1.0f / 512.0f);
    float inv = 1.0f / sqrtf(var + 1e-6f);
    #pragma unroll
    for (int i = 0; i < 8; i++) {
        int d = lane + i * 64;
        float o2 = g[d] * (v[i] - mu) * inv + bb[d];
        out[(size_t)row * D_MODEL + d] = o2;
        if (WRITEB) outb[(size_t)row * D_MODEL + d] = f2b(o2);
    }
}

extern "C" void kernel_launch(void* const* d_in, const int* in_sizes, int n_in,
                              void* d_out, int out_size, void* d_ws, size_t ws_size,
                              hipStream_t stream) {
    const int*   dec     = (const int*)d_in[0];
    const int*   enc_ids = (const int*)d_in[1];
    const float* enc_out = (const float*)d_in[2];
    const float* emb     = (const float*)d_in[3];
    const float* self_W  = (const float*)d_in[4];
    const float* self_b  = (const float*)d_in[5];
    const float* enc_W   = (const float*)d_in[6];
    const float* enc_b   = (const float*)d_in[7];
    const float* W1      = (const float*)d_in[8];
    const float* b1      = (const float*)d_in[9];
    const float* W2      = (const float*)d_in[10];
    const float* b2      = (const float*)d_in[11];
    const float* ln_g    = (const float*)d_in[12];
    const float* ln_b    = (const float*)d_in[13];
    float* out = (float*)d_out;

    const size_t NTOK = (size_t)BSZ * SEQ;      // 4096
    float* x  = (float*)d_ws;
    float* bA = x + NTOK * D_MODEL;
    unsigned short* xb   = (unsigned short*)(bA + NTOK * D_MODEL);
    unsigned short* encb = xb + NTOK * D_MODEL;
    unsigned short* bQ = encb + NTOK * D_MODEL;
    unsigned short* bK = bQ + NTOK * D_MODEL;
    unsigned short* bV = bK + NTOK * D_MODEL;
    unsigned short* bD = bV + NTOK * D_MODEL;
    unsigned short* bH = bQ;                    // 4096*2048 bf16 aliases bQ..bD
    unsigned short* wtS  = bD + NTOK * D_MODEL;
    unsigned short* wtE  = wtS + (size_t)N_LAYERS * 4 * D_MODEL * D_MODEL;
    unsigned short* wtF1 = wtE + (size_t)N_LAYERS * 4 * D_MODEL * D_MODEL;
    unsigned short* wtF2 = wtF1 + (size_t)N_LAYERS * D_MODEL * D_FF;
    int* cntEnc    = (int*)(wtF2 + (size_t)N_LAYERS * D_FF * D_MODEL);
    int* anyPadDec = cntEnc + BSZ;
    int* listEnc   = anyPadDec + BSZ * (SEQ / 64);

    dim3 blk(256);
    embed_kernel<<<dim3((unsigned)(NTOK * D_MODEL / 256)), blk, 0, stream>>>(dec, emb, x, xb);
    cvt_bf16_kernel<<<dim3((unsigned)(NTOK * D_MODEL / 4 / 256)), blk, 0, stream>>>(enc_out, encb, (int)(NTOK * D_MODEL / 4));
    prep_kernel<<<dim3(BSZ), dim3(64), 0, stream>>>(dec, enc_ids, cntEnc, listEnc, anyPadDec);
    wt_kernel<<<dim3(8, 8, 16), blk, 0, stream>>>(self_W, wtS, D_MODEL, D_MODEL);
    wt_kernel<<<dim3(8, 8, 16), blk, 0, stream>>>(enc_W,  wtE, D_MODEL, D_MODEL);
    wt_kernel<<<dim3(8, 32, 4), blk, 0, stream>>>(W1, wtF1, D_MODEL, D_FF);
    wt_kernel<<<dim3(32, 8, 4), blk, 0, stream>>>(W2, wtF2, D_FF, D_MODEL);

    int M = (int)NTOK;
    dim3 gqkv(M / 128, 12);            // merged QKV (128x128 tiles): 384 blocks
    dim3 gp  (M / 128, D_MODEL / 64);  // proj (128x64): 256 blocks
    dim3 gf1 (M / 128, D_FF / 128);    // FFN1 (128x128): 512 blocks
    dim3 gf2 (M / 128, D_MODEL / 64);  // FFN2 (128x64): 256 blocks
    int nAttnBlk = BSZ * N_HEADS * (SEQ / 64);

    const size_t WT = (size_t)D_MODEL * D_MODEL;
    for (int L = 0; L < N_LAYERS; L++) {
        const unsigned short* sWt = wtS + (size_t)L * 4 * WT;
        const unsigned short* eWt = wtE + (size_t)L * 4 * WT;
        const float* sb = self_b + (size_t)L * 4 * D_MODEL;
        const float* eb = enc_b  + (size_t)L * 4 * D_MODEL;
        const float* g  = ln_g   + (size_t)L * 3 * D_MODEL;
        const float* bs = ln_b   + (size_t)L * 3 * D_MODEL;

        // ---- self attention ----
        gemm128_kernel<1,0,1><<<gqkv, blk, 0, stream>>>(xb, xb, sWt, sb, bQ, bK, bV, M, D_MODEL, D_MODEL);
        attn_kernel<1><<<dim3(nAttnBlk), blk, 0, stream>>>(bQ, bK, bV, dec, listEnc, cntEnc, anyPadDec, bD, SEQ, SEQ);
        gemm_lds_kernel<0,0><<<gp, blk, 0, stream>>>(bD, sWt + 3 * WT, sb + 3 * D_MODEL, bA, M, D_MODEL, D_MODEL);
        ln_residual_kernel<1><<<dim3(M / 4), blk, 0, stream>>>(bA, x, g + 0 * D_MODEL, bs + 0 * D_MODEL, x, xb);

        // ---- cross attention ----
        gemm128_kernel<1,0,1><<<gqkv, blk, 0, stream>>>(xb, encb, eWt, eb, bQ, bK, bV, M, D_MODEL, D_MODEL);
        attn_kernel<0><<<dim3(nAttnBlk), blk, 0, stream>>>(bQ, bK, bV, enc_ids, listEnc, cntEnc, anyPadDec, bD, SEQ, SEQ);
        gemm_lds_kernel<0,0><<<gp, blk, 0, stream>>>(bD, eWt + 3 * WT, eb + 3 * D_MODEL, bA, M, D_MODEL, D_MODEL);
        ln_residual_kernel<1><<<dim3(M / 4), blk, 0, stream>>>(bA, x, g + 1 * D_MODEL, bs + 1 * D_MODEL, x, xb);

        // ---- FFN ----
        gemm128_kernel<1,1,0><<<gf1, blk, 0, stream>>>(xb, nullptr, wtF1 + (size_t)L * D_MODEL * D_FF, b1 + (size_t)L * D_FF,    bH, nullptr, nullptr, M, D_FF,    D_MODEL);
        gemm_lds_kernel<0,0><<<gf2, blk, 0, stream>>>(bH, wtF2 + (size_t)L * D_FF * D_MODEL, b2 + (size_t)L * D_MODEL, bA, M, D_MODEL, D_FF);
        float* lnout = (L == N_LAYERS - 1) ? out : x;
        ln_residual_kernel<1><<<dim3(M / 4), blk, 0, stream>>>(bA, x, g + 2 * D_MODEL, bs + 2 * D_MODEL, lnout, xb);
    }
}